// Round 7
// baseline (413.672 us; speedup 1.0000x reference)
//
#include <hip/hip_runtime.h>

// Encoder: B=512, T=128, N=128, H=256
// Round 11:
//  k_attn: Q/Wv moved OFF the LDS pipe onto the scalar path. All Q reads are
//          wave-uniform -> readfirstlane-forced uniform loads (s_load; safe
//          fallback = HW-merged broadcast global_load). Q consumed from
//          Qt[b][tau][t] (produced transposed by MODE1). No qs_t staging ->
//          bank conflicts gone; LDS = epart+red only. Packed f32x2 math
//          identical to Round 10; -2 folded into epart write (exact linear).
//  k_gemm<256,1>: epilogue stages C-tile in LDS (stride 129, 2-way free) and
//          writes Qt[b][tau][t] with coalesced float4-over-t stores.
//  k_rnn : 512 thr (8 waves x 32 cols), distance-2 xw prefetch (two named
//          buffers, reload after consume) -> HBM latency off critical path.
//          Hb relaid [b][t][col] to match MODE1 tiling.
// Workspace (f32 offsets): P 0 | xw/Qt 8388608 | Hb(hf) 25165824 | wts(hf) 33554432

#define C2L 2.8853900817779268f   // 2*log2(e)
#define L2E 1.4426950408889634f   // log2(e)

typedef _Float16 hf;
typedef _Float16 hf4 __attribute__((ext_vector_type(4)));
typedef _Float16 hf8 __attribute__((ext_vector_type(8)));
typedef float f32x4 __attribute__((ext_vector_type(4)));
typedef float f32x2 __attribute__((ext_vector_type(2)));

__device__ __forceinline__ float fast_exp2(float x){
#if __has_builtin(__builtin_amdgcn_exp2f)
  return __builtin_amdgcn_exp2f(x);
#else
  return exp2f(x);
#endif
}
__device__ __forceinline__ float fast_rcp(float x){
#if __has_builtin(__builtin_amdgcn_rcpf)
  return __builtin_amdgcn_rcpf(x);
#else
  return 1.f/x;
#endif
}
__device__ __forceinline__ f32x2 bc(float s){ return (f32x2){s, s}; }
__device__ __forceinline__ f32x2 fma2(f32x2 a, f32x2 b, f32x2 c){
  return __builtin_elementwise_fma(a, b, c);
}
// wave-uniform float4 load (offset forced to SGPR; identity when uniform)
__device__ __forceinline__ float4 uld4(const float* __restrict__ p, int off){
  off = __builtin_amdgcn_readfirstlane(off);
  return *(const float4*)(p + off);
}

// ---------------- weight prep: f32 [k][n] -> f16 [n][k] ----------------
__global__ __launch_bounds__(256) void k_prep_w(const float* __restrict__ Wx,
    const float* __restrict__ W2, const float* __restrict__ W1,
    hf* __restrict__ wts){
  int tid = blockIdx.x*256 + threadIdx.x;   // 320 blocks -> 81920 threads
  if (tid < 32768){                          // Wxt[n<256][k<128]
    int n = tid >> 7, k = tid & 127;
    wts[tid] = (hf)Wx[k*256 + n];
  } else if (tid < 65536){                   // W2t[n<128][k<256]
    int t2 = tid - 32768;
    int n = t2 >> 8, k = t2 & 255;
    wts[tid] = (hf)W2[k*128 + n];
  } else {                                   // W1t[n<128][k<128]
    int t3 = tid - 65536;
    int n = t3 >> 7, k = t3 & 127;
    wts[tid] = (hf)W1[k*128 + n];
  }
}

// ---------------- unified MFMA GEMM ----------------
// block = 256 thr (4 waves). Tile: M=64 (wave strip 16), N=128, K chunked by 128.
// smem: As[64][136] + Bs[128][136] f16 = 52,224 B (MODE1 reuses as Cs[64][129] f32).
template<int K, int MODE>
__global__ __launch_bounds__(256) void k_gemm(const void* __restrict__ Asrc,
    const hf* __restrict__ Bt, const float* __restrict__ bias,
    float* __restrict__ Cout){
  constexpr int SA = 136;
  __shared__ alignas(16) char smem[64*SA*2 + 128*SA*2];
  hf* As = (hf*)smem;
  hf* Bs = (hf*)(smem + 64*SA*2);
  const int tid = threadIdx.x;
  const int w = tid >> 6, lane = tid & 63;
  const int c = lane & 15, q = lane >> 4;
  const int bx = blockIdx.x;
  const int col0 = (MODE==0) ? blockIdx.y*128 : 0;

  float br[8];
  #pragma unroll
  for (int ni=0; ni<8; ni++) br[ni] = bias[col0 + ni*16 + c];

  f32x4 acc[8];
  #pragma unroll
  for (int ni=0; ni<8; ni++) acc[ni] = (f32x4){0.f,0.f,0.f,0.f};

  for (int kc=0; kc<K/128; kc++){
    // ---- stage A chunk (64 rows x 128 k) ----
    if (MODE == 0){
      const float* A = (const float*)Asrc + (long)bx*64*128;
      #pragma unroll
      for (int v=0; v<8; v++){
        int f4 = v*256 + tid;
        int m = f4 >> 5, k4 = (f4 & 31)*4;
        float4 d = *(const float4*)&A[m*128 + k4];
        hf4 h = {(hf)d.x,(hf)d.y,(hf)d.z,(hf)d.w};
        *(hf4*)&As[m*SA + k4] = h;
      }
    } else if (MODE == 1){
      const hf* A = (const hf*)Asrc + (long)bx*64*256;
      #pragma unroll
      for (int v=0; v<4; v++){
        int f8 = v*256 + tid;
        int m = f8 >> 4, k8 = (f8 & 15)*8;
        *(hf8*)&As[m*SA + k8] = *(const hf8*)&A[m*256 + kc*128 + k8];
      }
    } else {
      const float* A = (const float*)Asrc + (long)(bx>>1)*16384;
      const int i0 = (bx & 1)*64;
      #pragma unroll
      for (int v=0; v<8; v++){
        int f4 = v*256 + tid;
        int t = f4 >> 4, i4 = (f4 & 15)*4;
        float4 d = *(const float4*)&A[t*128 + i0 + i4];
        As[(i4+0)*SA + t] = (hf)d.x;
        As[(i4+1)*SA + t] = (hf)d.y;
        As[(i4+2)*SA + t] = (hf)d.z;
        As[(i4+3)*SA + t] = (hf)d.w;
      }
    }
    // ---- stage B chunk (128 n x 128 k), Bt is f16 [n][K] ----
    #pragma unroll
    for (int v=0; v<8; v++){
      int f8 = v*256 + tid;
      int n = f8 >> 4, k8 = (f8 & 15)*8;
      *(hf8*)&Bs[n*SA + k8] = *(const hf8*)&Bt[(col0+n)*K + kc*128 + k8];
    }
    __syncthreads();
    // ---- MFMA ----
    #pragma unroll
    for (int kk=0; kk<4; kk++){
      hf8 a = *(const hf8*)&As[(w*16 + c)*SA + kk*32 + q*8];
      #pragma unroll
      for (int ni=0; ni<8; ni++){
        hf8 b = *(const hf8*)&Bs[(ni*16 + c)*SA + kk*32 + q*8];
        acc[ni] = __builtin_amdgcn_mfma_f32_16x16x32_f16(a, b, acc[ni], 0, 0, 0);
      }
    }
    __syncthreads();
  }
  // ---- epilogue ----
  if (MODE == 1){
    // Stage C-tile (64 t-rows x 128 tau) in LDS, then write Qt[b][tau][t]
    // coalesced along t. Rows of A are Hb's [b][t] flattening:
    // R = bx*64 + rloc -> b_ = bx>>1, t = (bx&1)*64 + rloc.
    float* Cs = (float*)smem;                 // [64][129] f32 = 33,024 B
    #pragma unroll
    for (int ni=0; ni<8; ni++){
      #pragma unroll
      for (int r=0; r<4; r++){
        int rloc = w*16 + q*4 + r;
        Cs[rloc*129 + ni*16 + c] = acc[ni][r] + br[ni];
      }
    }
    __syncthreads();
    const int b_  = bx >> 1;
    const int t0_ = (bx & 1) * 64;
    const int tq  = (tid & 15) * 4;           // local t quad
    #pragma unroll
    for (int jj=0; jj<8; jj++){
      int tau = jj*16 + (tid >> 4);
      float4 o;
      o.x = fast_exp2(C2L * Cs[(tq+0)*129 + tau]);
      o.y = fast_exp2(C2L * Cs[(tq+1)*129 + tau]);
      o.z = fast_exp2(C2L * Cs[(tq+2)*129 + tau]);
      o.w = fast_exp2(C2L * Cs[(tq+3)*129 + tau]);
      *(float4*)&Cout[((long)b_*128 + tau)*128 + t0_ + tq] = o;
    }
  } else {
    #pragma unroll
    for (int ni=0; ni<8; ni++){
      #pragma unroll
      for (int r=0; r<4; r++){
        int rloc = w*16 + q*4 + r;
        int col = col0 + ni*16 + c;
        float val = acc[ni][r] + br[ni];
        int addr;
        if (MODE == 0){
          int R = bx*64 + rloc;
          int b2_ = R >> 7, t2_ = R & 127;
          addr = (t2_*512 + b2_)*256 + col;
        } else {
          int b2_ = bx >> 1, i_ = (bx & 1)*64 + rloc;
          addr = b2_*16384 + i_*128 + col;
          val = fast_exp2(C2L*val);
        }
        Cout[addr] = val;
      }
    }
  }
}

// ---------------- recurrence (MFMA, 8 waves, dist-2 prefetch) ----------------
// 32 blocks x 512 thr. Block owns batches [16*bx,16*bx+16); wave w owns cols
// [32w,32w+32): 2 n-tiles, Wh B-frags 64 VGPR/lane (loaded once).
// h[16][256] hf ping-pongs in LDS, XOR slot-swizzle (slot ^= row&7) ->
// A-frag ds_read_b128 conflict-free. xw prefetch DISTANCE 2: two named
// buffers; each reloaded for t+2 right after its step consumes it, so the
// HBM load has ~2 full steps to complete. Hb written f16 in [b][t][col].
__device__ __forceinline__ void rnn_step(int T, int b0, int w0, int c, int q,
    char* hs, const hf8 (&bw)[2][8], float (&buf)[2][4],
    const float* __restrict__ xw, hf* __restrict__ Hb){
  const int p = T & 1;
  const int abase = c*512;
  hf8 a[8];
  #pragma unroll
  for (int kc=0; kc<8; kc++)
    a[kc] = *(const hf8*)&hs[p*8192 + abase + ((((kc<<2)|q) ^ (c & 7)) << 4)];
  f32x4 ac0a = (f32x4){0.f,0.f,0.f,0.f}, ac0b = ac0a;
  f32x4 ac1a = ac0a, ac1b = ac0a;
  #pragma unroll
  for (int kc=0; kc<4; kc++){
    ac0a = __builtin_amdgcn_mfma_f32_16x16x32_f16(a[kc],   bw[0][kc],   ac0a,0,0,0);
    ac0b = __builtin_amdgcn_mfma_f32_16x16x32_f16(a[kc+4], bw[0][kc+4], ac0b,0,0,0);
    ac1a = __builtin_amdgcn_mfma_f32_16x16x32_f16(a[kc],   bw[1][kc],   ac1a,0,0,0);
    ac1b = __builtin_amdgcn_mfma_f32_16x16x32_f16(a[kc+4], bw[1][kc+4], ac1b,0,0,0);
  }
  #pragma unroll
  for (int nt=0; nt<2; nt++){
    #pragma unroll
    for (int r=0; r<4; r++){
      float v = (nt ? (ac1a[r]+ac1b[r]) : (ac0a[r]+ac0b[r])) + buf[nt][r];
      float e2 = fast_exp2(v*C2L);
      float hn = 1.f - 2.f*fast_rcp(e2 + 1.f);
      int row = q*4 + r;
      int col = w0 + nt*16 + c;
      *(hf*)&hs[(p^1)*8192 + row*512
                + (((col >> 3) ^ (row & 7)) << 4) + (col & 7)*2] = (hf)hn;
      Hb[((long)(b0 + row)*128 + T)*256 + col] = (hf)hn;
    }
  }
  // reload this buffer for step T+2 (consumed two steps from now)
  #pragma unroll
  for (int nt=0; nt<2; nt++){
    #pragma unroll
    for (int r=0; r<4; r++){
      buf[nt][r] = (T+2 < 128)
        ? xw[((T+2)*512 + b0 + q*4 + r)*256 + w0 + nt*16 + c] : 0.f;
    }
  }
}

__global__ __launch_bounds__(512, 2) void k_rnn(const float* __restrict__ h0,
    const float* __restrict__ Wh, const float* __restrict__ xw,
    hf* __restrict__ Hb){
  __shared__ alignas(16) char hs[2*8192];   // [parity][16 rows x 512B]
  const int tid = threadIdx.x;
  const int w = tid >> 6, lane = tid & 63;
  const int c = lane & 15, q = lane >> 4;
  const int b0 = blockIdx.x * 16;
  const int w0 = w * 32;
  // ---- Wh B-frags (one-time) ----
  hf8 bw[2][8];
  #pragma unroll
  for (int nt=0; nt<2; nt++){
    #pragma unroll
    for (int kc=0; kc<8; kc++){
      #pragma unroll
      for (int e=0; e<8; e++){
        bw[nt][kc][e] = (hf)Wh[(kc*32 + q*8 + e)*256 + w0 + nt*16 + c];
      }
    }
  }
  // ---- stage h0 -> hs[parity 0], swizzled ----
  {
    int m = tid >> 5, s8 = tid & 31;
    const float* src = &h0[(b0 + m)*256 + s8*8];
    float4 d0 = *(const float4*)&src[0];
    float4 d1 = *(const float4*)&src[4];
    hf8 hv = {(hf)d0.x,(hf)d0.y,(hf)d0.z,(hf)d0.w,
              (hf)d1.x,(hf)d1.y,(hf)d1.z,(hf)d1.w};
    *(hf8*)&hs[m*512 + ((s8 ^ (m & 7)) << 4)] = hv;
  }
  // ---- prologue: load xw for t=0 (bufA) and t=1 (bufB) ----
  float bufA[2][4], bufB[2][4];
  #pragma unroll
  for (int nt=0; nt<2; nt++){
    #pragma unroll
    for (int r=0; r<4; r++){
      bufA[nt][r] = xw[(0*512 + b0 + q*4 + r)*256 + w0 + nt*16 + c];
      bufB[nt][r] = xw[(1*512 + b0 + q*4 + r)*256 + w0 + nt*16 + c];
    }
  }
  __syncthreads();
  for (int t=0; t<128; t+=2){
    rnn_step(t,   b0, w0, c, q, hs, bw, bufA, xw, Hb);
    __syncthreads();
    rnn_step(t+1, b0, w0, c, q, hs, bw, bufB, xw, Hb);
    __syncthreads();
  }
}

// ---------------- attention + softmax + scale ----------------
// grid (512 b, 4 t-tiles), 512 threads. Thread = (i, tau-quarter g of 32).
// P quarter in registers (8 float4). Q read from Qt[b][tau][t] via wave-
// uniform scalar loads (no LDS, no VALU); Wv likewise, with the -2 factor
// folded into the epart write (exact linear scaling).
// Inner loop packed over t (f32x2 -> v_pk_fma_f32/v_pk_mul_f32), 4-way rcp
// sharing; per-element math identical to Rounds 7/10.
__global__ __launch_bounds__(512, 4) void k_attn(const float* __restrict__ P,
    const float* __restrict__ Qt, const float* __restrict__ Wv,
    const float* __restrict__ data, float* __restrict__ out){
  __shared__ alignas(16) float epart[2][4][4][128]; // [parity][quar][tl][i] 16KB
  __shared__ float red[2][4][2];                    // [parity][tl][half]
  const int b = blockIdx.x, tile = blockIdx.y;
  const int tid = threadIdx.x;
  const int i = tid & 127, g = tid >> 7;            // i, tau-quarter 0..3
  const int t0 = tile*32;
  // P quarter -> registers
  float4 p4[8];
  const float* prow = P + b*16384 + i*128 + g*32;
  #pragma unroll
  for (int v=0; v<8; v++) p4[v] = *(const float4*)&prow[v*4];
  // Wv quarter -> uniform (SGPR) registers, raw (no -2)
  float4 wvv[8];
  #pragma unroll
  for (int mm=0; mm<8; mm++) wvv[mm] = uld4(Wv, g*32 + mm*4);
  const int qbase = (b*128 + g*32)*128 + t0;        // wave-uniform
  const f32x2 ONE2 = {1.f, 1.f};
  for (int tp=0; tp<8; tp++){
    const int pp = tp & 1;
    const int qo = qbase + 4*tp;
    f32x2 ACC01 = {0.f,0.f}, ACC23 = {0.f,0.f};
    #pragma unroll
    for (int mm=0; mm<8; mm++){
      float4 qa = uld4(Qt, qo + (mm*4+0)*128);
      float4 qb = uld4(Qt, qo + (mm*4+1)*128);
      float4 qc = uld4(Qt, qo + (mm*4+2)*128);
      float4 qd = uld4(Qt, qo + (mm*4+3)*128);
      float4 Pv = p4[mm];
      float4 wv = wvv[mm];
      // ---- t-pair (t0,t1) ----
      {
        f32x2 Qa = {qa.x, qa.y}, Qb = {qb.x, qb.y};
        f32x2 Qc = {qc.x, qc.y}, Qd = {qd.x, qd.y};
        f32x2 Ua = fma2(bc(Pv.x), Qa, ONE2);
        f32x2 Ub = fma2(bc(Pv.y), Qb, ONE2);
        f32x2 Uc = fma2(bc(Pv.z), Qc, ONE2);
        f32x2 Ud = fma2(bc(Pv.w), Qd, ONE2);
        f32x2 dab = Ua*Ub, dcd = Uc*Ud;
        f32x2 nab = fma2(bc(wv.x), Ub, bc(wv.y)*Ua);
        f32x2 ncd = fma2(bc(wv.z), Ud, bc(wv.w)*Uc);
        f32x2 D = dab*dcd;
        f32x2 N = fma2(nab, dcd, ncd*dab);
        f32x2 R = {fast_rcp(D.x), fast_rcp(D.y)};
        ACC01 = fma2(N, R, ACC01);
      }
      // ---- t-pair (t2,t3) ----
      {
        f32x2 Qa = {qa.z, qa.w}, Qb = {qb.z, qb.w};
        f32x2 Qc = {qc.z, qc.w}, Qd = {qd.z, qd.w};
        f32x2 Ua = fma2(bc(Pv.x), Qa, ONE2);
        f32x2 Ub = fma2(bc(Pv.y), Qb, ONE2);
        f32x2 Uc = fma2(bc(Pv.z), Qc, ONE2);
        f32x2 Ud = fma2(bc(Pv.w), Qd, ONE2);
        f32x2 dab = Ua*Ub, dcd = Uc*Ud;
        f32x2 nab = fma2(bc(wv.x), Ub, bc(wv.y)*Ua);
        f32x2 ncd = fma2(bc(wv.z), Ud, bc(wv.w)*Uc);
        f32x2 D = dab*dcd;
        f32x2 N = fma2(nab, dcd, ncd*dab);
        f32x2 R = {fast_rcp(D.x), fast_rcp(D.y)};
        ACC23 = fma2(N, R, ACC23);
      }
    }
    epart[pp][g][0][i] = -2.f*ACC01.x;
    epart[pp][g][1][i] = -2.f*ACC01.y;
    epart[pp][g][2][i] = -2.f*ACC23.x;
    epart[pp][g][3][i] = -2.f*ACC23.y;
    __syncthreads();
    // thread handles tl = g for the reduction + output
    float e = epart[pp][0][g][i] + epart[pp][1][g][i]
            + epart[pp][2][g][i] + epart[pp][3][g][i];
    float pe = fast_exp2(e*L2E);
    float sm = pe;
    #pragma unroll
    for (int off=32; off; off>>=1) sm += __shfl_xor(sm, off);
    if ((tid & 63) == 0) red[pp][g][(tid>>6)&1] = sm;
    __syncthreads();
    float ssum = red[pp][g][0] + red[pp][g][1];
    float alpha = pe * fast_rcp(ssum);
    int t = t0 + 4*tp + g;
    int base = (t*512 + b)*128 + i;
    out[base] = data[base]*alpha;
  }
}

extern "C" void kernel_launch(void* const* d_in, const int* in_sizes, int n_in,
                              void* d_out, int out_size, void* d_ws, size_t ws_size,
                              hipStream_t stream) {
  const float* data = (const float*)d_in[0];
  const float* h0   = (const float*)d_in[1];
  const float* Wx   = (const float*)d_in[2];
  const float* Wh   = (const float*)d_in[3];
  const float* bb   = (const float*)d_in[4];
  const float* W1   = (const float*)d_in[5];
  const float* b1   = (const float*)d_in[6];
  const float* W2   = (const float*)d_in[7];
  const float* b2   = (const float*)d_in[8];
  const float* Wv   = (const float*)d_in[9];
  // d_in[10] = bv: softmax-invariant constant, dropped. d_in[11] = n (128).
  float* wsp = (float*)d_ws;
  float* Pm  = wsp;                         //  8,388,608 f
  float* xwQ = wsp + 8388608;               // 16,777,216 f (xw, then Qt[b][tau][t])
  hf*    Hbf = (hf*)(wsp + 25165824);       // 16,777,216 hf ([b][t][256])
  hf*    wts = (hf*)(wsp + 33554432);       // 81,920 hf
  const hf* Wxt = wts;                      // [256][128]
  const hf* W2t = wts + 32768;              // [128][256]
  const hf* W1t = wts + 65536;              // [128][128]
  float* out = (float*)d_out;

  hipLaunchKernelGGL(k_prep_w, dim3(320), dim3(256), 0, stream, Wx, W2, W1, wts);
  hipLaunchKernelGGL((k_gemm<128,0>), dim3(1024,2), dim3(256), 0, stream,
                     (const void*)data, Wxt, bb, xwQ);
  hipLaunchKernelGGL((k_gemm<128,2>), dim3(1024),   dim3(256), 0, stream,
                     (const void*)data, W1t, b1, Pm);
  hipLaunchKernelGGL(k_rnn, dim3(32), dim3(512), 0, stream, h0, Wh, xwQ, Hbf);
  hipLaunchKernelGGL((k_gemm<256,1>), dim3(1024),   dim3(256), 0, stream,
                     (const void*)Hbf, W2t, b2, xwQ);
  hipLaunchKernelGGL(k_attn, dim3(512, 4), dim3(512), 0, stream, Pm, xwQ, Wv, data, out);
}

// Round 8
// 372.775 us; speedup vs baseline: 1.1097x; 1.1097x over previous
//
#include <hip/hip_runtime.h>

// Encoder: B=512, T=128, N=128, H=256
// Round 12: base = Round-7 source (best measured: 354 µs; k_attn 120 µs).
//   ONLY k_rnn changed (layouts byte-identical to Round 7):
//   - 8 waves x 512 thr (was 16 x 1024): wave owns 32 cols, a-frags shared
//     across 2 n-tile chains -> per-CU LDS ds_read_b128 halves (64/step).
//   - distance-2 xw prefetch: two named buffers, each reloaded right after
//     its step consumes it -> HBM latency covered by a full step + barriers.
//   - paired-rcp tanh epilogue: rcp(ea*eb) serves 2 outputs (8 exp + 4 rcp).
//  k_attn: Round-7 scalar 4-way-rcp version (VALU-bound at 104%, proven).
//  k_gemm<K,MODE>: Round-7 version. k_prep_w: Round-7 version.
// Workspace (f32 offsets): P 0 | xw/Q 8388608 | Hb(hf) 25165824 | wts(hf) 33554432

#define C2L 2.8853900817779268f   // 2*log2(e)
#define L2E 1.4426950408889634f   // log2(e)

typedef _Float16 hf;
typedef _Float16 hf4 __attribute__((ext_vector_type(4)));
typedef _Float16 hf8 __attribute__((ext_vector_type(8)));
typedef float f32x4 __attribute__((ext_vector_type(4)));

__device__ __forceinline__ float fast_exp2(float x){
#if __has_builtin(__builtin_amdgcn_exp2f)
  return __builtin_amdgcn_exp2f(x);
#else
  return exp2f(x);
#endif
}
__device__ __forceinline__ float fast_rcp(float x){
#if __has_builtin(__builtin_amdgcn_rcpf)
  return __builtin_amdgcn_rcpf(x);
#else
  return 1.f/x;
#endif
}

// ---------------- weight prep: f32 [k][n] -> f16 [n][k] ----------------
__global__ __launch_bounds__(256) void k_prep_w(const float* __restrict__ Wx,
    const float* __restrict__ W2, const float* __restrict__ W1,
    hf* __restrict__ wts){
  int tid = blockIdx.x*256 + threadIdx.x;   // 320 blocks -> 81920 threads
  if (tid < 32768){                          // Wxt[n<256][k<128]
    int n = tid >> 7, k = tid & 127;
    wts[tid] = (hf)Wx[k*256 + n];
  } else if (tid < 65536){                   // W2t[n<128][k<256]
    int t2 = tid - 32768;
    int n = t2 >> 8, k = t2 & 255;
    wts[tid] = (hf)W2[k*128 + n];
  } else {                                   // W1t[n<128][k<128]
    int t3 = tid - 65536;
    int n = t3 >> 7, k = t3 & 127;
    wts[tid] = (hf)W1[k*128 + n];
  }
}

// ---------------- unified MFMA GEMM ----------------
// block = 256 thr (4 waves). Tile: M=64 (wave strip 16), N=128, K chunked by 128.
// LDS: As[64][136] + Bs[128][136] f16 = 52,224 B.
template<int K, int MODE>
__global__ __launch_bounds__(256) void k_gemm(const void* __restrict__ Asrc,
    const hf* __restrict__ Bt, const float* __restrict__ bias,
    float* __restrict__ Cout){
  constexpr int SA = 136;
  __shared__ alignas(16) hf As[64*SA];
  __shared__ alignas(16) hf Bs[128*SA];
  const int tid = threadIdx.x;
  const int w = tid >> 6, lane = tid & 63;
  const int c = lane & 15, q = lane >> 4;
  const int bx = blockIdx.x;
  const int col0 = (MODE==0) ? blockIdx.y*128 : 0;

  float br[8];
  #pragma unroll
  for (int ni=0; ni<8; ni++) br[ni] = bias[col0 + ni*16 + c];

  f32x4 acc[8];
  #pragma unroll
  for (int ni=0; ni<8; ni++) acc[ni] = (f32x4){0.f,0.f,0.f,0.f};

  for (int kc=0; kc<K/128; kc++){
    // ---- stage A chunk (64 rows x 128 k) ----
    if (MODE == 0){
      const float* A = (const float*)Asrc + (long)bx*64*128;
      #pragma unroll
      for (int v=0; v<8; v++){
        int f4 = v*256 + tid;
        int m = f4 >> 5, k4 = (f4 & 31)*4;
        float4 d = *(const float4*)&A[m*128 + k4];
        hf4 h = {(hf)d.x,(hf)d.y,(hf)d.z,(hf)d.w};
        *(hf4*)&As[m*SA + k4] = h;
      }
    } else if (MODE == 1){
      const hf* A = (const hf*)Asrc + (long)bx*64*256;
      #pragma unroll
      for (int v=0; v<4; v++){
        int f8 = v*256 + tid;
        int m = f8 >> 4, k8 = (f8 & 15)*8;
        *(hf8*)&As[m*SA + k8] = *(const hf8*)&A[m*256 + kc*128 + k8];
      }
    } else {
      const float* A = (const float*)Asrc + (long)(bx>>1)*16384;
      const int i0 = (bx & 1)*64;
      #pragma unroll
      for (int v=0; v<8; v++){
        int f4 = v*256 + tid;
        int t = f4 >> 4, i4 = (f4 & 15)*4;
        float4 d = *(const float4*)&A[t*128 + i0 + i4];
        As[(i4+0)*SA + t] = (hf)d.x;
        As[(i4+1)*SA + t] = (hf)d.y;
        As[(i4+2)*SA + t] = (hf)d.z;
        As[(i4+3)*SA + t] = (hf)d.w;
      }
    }
    // ---- stage B chunk (128 n x 128 k), Bt is f16 [n][K] ----
    #pragma unroll
    for (int v=0; v<8; v++){
      int f8 = v*256 + tid;
      int n = f8 >> 4, k8 = (f8 & 15)*8;
      *(hf8*)&Bs[n*SA + k8] = *(const hf8*)&Bt[(col0+n)*K + kc*128 + k8];
    }
    __syncthreads();
    // ---- MFMA ----
    #pragma unroll
    for (int kk=0; kk<4; kk++){
      hf8 a = *(const hf8*)&As[(w*16 + c)*SA + kk*32 + q*8];
      #pragma unroll
      for (int ni=0; ni<8; ni++){
        hf8 b = *(const hf8*)&Bs[(ni*16 + c)*SA + kk*32 + q*8];
        acc[ni] = __builtin_amdgcn_mfma_f32_16x16x32_f16(a, b, acc[ni], 0, 0, 0);
      }
    }
    __syncthreads();
  }
  // ---- epilogue ----
  #pragma unroll
  for (int ni=0; ni<8; ni++){
    #pragma unroll
    for (int r=0; r<4; r++){
      int rloc = w*16 + q*4 + r;
      int col = col0 + ni*16 + c;
      float val = acc[ni][r] + br[ni];
      int addr;
      if (MODE == 0){
        int R = bx*64 + rloc;
        int b_ = R >> 7, t_ = R & 127;
        addr = (t_*512 + b_)*256 + col;
      } else if (MODE == 1){
        int R = bx*64 + rloc;
        addr = R*128 + col;
        val = fast_exp2(C2L*val);
      } else {
        int b_ = bx >> 1, i_ = (bx & 1)*64 + rloc;
        addr = b_*16384 + i_*128 + col;
        val = fast_exp2(C2L*val);
      }
      Cout[addr] = val;
    }
  }
}

// ---------------- recurrence (MFMA, 8 waves, dist-2 prefetch) ----------------
// 32 blocks x 512 thr. Block owns batches [16*bx,16*bx+16); wave w owns cols
// [32w,32w+32): 2 n-tiles fed by SHARED a-frags (8 ds_read, 16 MFMA / wave).
// h[16][256] hf ping-pongs in LDS, XOR slot-swizzle (slot ^= row&7) ->
// A-frag ds_read_b128 conflict-free. xw prefetch distance 2: bufA/bufB
// reloaded immediately after consumption (v computed) -> load latency covered
// by transcendentals + stores + barrier + the other step. Paired-rcp tanh.
// Layouts identical to Round 7: xw[t][b][col], Hb[t][b][col].
__global__ __launch_bounds__(512, 2) void k_rnn(const float* __restrict__ h0,
    const float* __restrict__ Wh, const float* __restrict__ xw,
    hf* __restrict__ Hb){
  __shared__ alignas(16) char hs[2*8192];   // [parity][16 rows x 512B]
  const int tid = threadIdx.x;
  const int w = tid >> 6, lane = tid & 63;
  const int c = lane & 15, q = lane >> 4;
  const int b0 = blockIdx.x * 16;
  const int w0 = w * 32;
  // ---- Wh B-frags: bw[nt][kc][e] = Wh[kc*32+q*8+e][w0+nt*16+c] ----
  hf8 bw[2][8];
  #pragma unroll
  for (int nt=0; nt<2; nt++){
    #pragma unroll
    for (int kc=0; kc<8; kc++){
      #pragma unroll
      for (int e=0; e<8; e++){
        bw[nt][kc][e] = (hf)Wh[(kc*32 + q*8 + e)*256 + w0 + nt*16 + c];
      }
    }
  }
  // ---- stage h0 -> hs[parity 0], swizzled ----
  {
    int m = tid >> 5, s8 = tid & 31;           // row, 16B-slot
    const float* src = &h0[(b0 + m)*256 + s8*8];
    float4 d0 = *(const float4*)&src[0];
    float4 d1 = *(const float4*)&src[4];
    hf8 hv = {(hf)d0.x,(hf)d0.y,(hf)d0.z,(hf)d0.w,
              (hf)d1.x,(hf)d1.y,(hf)d1.z,(hf)d1.w};
    *(hf8*)&hs[m*512 + ((s8 ^ (m & 7)) << 4)] = hv;
  }
  // ---- prologue: xw for t=0 (bufA) and t=1 (bufB) ----
  float bufA[2][4], bufB[2][4];
  #pragma unroll
  for (int nt=0; nt<2; nt++){
    #pragma unroll
    for (int r=0; r<4; r++){
      bufA[nt][r] = xw[(0*512 + b0 + q*4 + r)*256 + w0 + nt*16 + c];
      bufB[nt][r] = xw[(1*512 + b0 + q*4 + r)*256 + w0 + nt*16 + c];
    }
  }
  __syncthreads();
  const int abase = c*512;
  #pragma unroll 1
  for (int t=0; t<128; t+=2){
    #pragma unroll
    for (int half=0; half<2; half++){
      const int T = t + half;
      const int p = T & 1;
      // ---- A-frags from LDS (swizzled, conflict-free) ----
      hf8 a[8];
      #pragma unroll
      for (int kc=0; kc<8; kc++)
        a[kc] = *(const hf8*)&hs[p*8192 + abase + ((((kc<<2)|q) ^ (c & 7)) << 4)];
      // ---- 4 independent 4-deep MFMA chains (a shared across n-tiles) ----
      f32x4 ac0a = (f32x4){0.f,0.f,0.f,0.f}, ac0b = ac0a;
      f32x4 ac1a = ac0a, ac1b = ac0a;
      #pragma unroll
      for (int kc=0; kc<4; kc++){
        ac0a = __builtin_amdgcn_mfma_f32_16x16x32_f16(a[kc],   bw[0][kc],   ac0a,0,0,0);
        ac1a = __builtin_amdgcn_mfma_f32_16x16x32_f16(a[kc],   bw[1][kc],   ac1a,0,0,0);
        ac0b = __builtin_amdgcn_mfma_f32_16x16x32_f16(a[kc+4], bw[0][kc+4], ac0b,0,0,0);
        ac1b = __builtin_amdgcn_mfma_f32_16x16x32_f16(a[kc+4], bw[1][kc+4], ac1b,0,0,0);
      }
      // ---- consume buf -> vv; immediately reload buf for T+2 ----
      float vv[2][4];
      #pragma unroll
      for (int r=0; r<4; r++){
        vv[0][r] = ac0a[r] + ac0b[r] + (half ? bufB[0][r] : bufA[0][r]);
        vv[1][r] = ac1a[r] + ac1b[r] + (half ? bufB[1][r] : bufA[1][r]);
      }
      #pragma unroll
      for (int nt=0; nt<2; nt++){
        #pragma unroll
        for (int r=0; r<4; r++){
          float nv = (T+2 < 128)
            ? xw[((T+2)*512 + b0 + q*4 + r)*256 + w0 + nt*16 + c] : 0.f;
          if (half) bufB[nt][r] = nv; else bufA[nt][r] = nv;
        }
      }
      // ---- tanh (paired rcp) + stores ----
      #pragma unroll
      for (int nt=0; nt<2; nt++){
        #pragma unroll
        for (int pr=0; pr<2; pr++){
          float ea = fast_exp2(vv[nt][2*pr+0]*C2L) + 1.f;
          float eb = fast_exp2(vv[nt][2*pr+1]*C2L) + 1.f;
          float R = fast_rcp(ea*eb);
          float h0v = fmaf(-2.f*eb, R, 1.f);
          float h1v = fmaf(-2.f*ea, R, 1.f);
          #pragma unroll
          for (int rr=0; rr<2; rr++){
            float hn = rr ? h1v : h0v;
            int row = q*4 + 2*pr + rr;
            int col = w0 + nt*16 + c;
            *(hf*)&hs[(p^1)*8192 + row*512
                      + (((col >> 3) ^ (row & 7)) << 4) + (col & 7)*2] = (hf)hn;
            Hb[(T*512 + b0 + row)*256 + col] = (hf)hn;
          }
        }
      }
      __syncthreads();
    }
  }
}

// ---------------- attention + softmax + scale ----------------
// grid (512 b, 4 t-tiles), 512 threads. Thread = (i, tau-quarter g of 32).
// P quarter in registers (8 float4 = 32 VGPR). Q tile (32 t) in LDS.
// 4-way rcp: w0/u+w1/v+w2/x+w3/y = (n01*d23+n23*d01)*rcp(d01*d23)
// -> 1 rcp per 4 taus. 4 timesteps per sweep; 2 barriers per sweep.
// No max in softmax (|e| <= sum|wv| ~ 5).
__global__ __launch_bounds__(512, 4) void k_attn(const float* __restrict__ P,
    const float* __restrict__ Qm, const float* __restrict__ Wv,
    const float* __restrict__ data, float* __restrict__ out){
  __shared__ alignas(16) float qs[32*128];          // [tt][tau] 16KB
  __shared__ alignas(16) float wvs[128];
  __shared__ alignas(16) float epart[2][4][4][128]; // [parity][quar][tl][i] 16KB
  __shared__ float red[2][4][2];                    // [parity][tl][half]
  const int b = blockIdx.x, tile = blockIdx.y;
  const int tid = threadIdx.x;
  const int i = tid & 127, g = tid >> 7;            // i, tau-quarter 0..3
  const int t0 = tile*32;
  if (tid < 128) wvs[tid] = -2.f*Wv[tid];
  #pragma unroll
  for (int v=0; v<2; v++){
    int flat = v*2048 + tid*4;
    int tt = flat >> 7, c = flat & 127;
    *(float4*)&qs[flat] = *(const float4*)&Qm[((t0+tt)*512 + b)*128 + c];
  }
  float4 p4[8];
  const float* prow = P + b*16384 + i*128 + g*32;
  #pragma unroll
  for (int v=0; v<8; v++) p4[v] = *(const float4*)&prow[v*4];
  __syncthreads();
  for (int tp=0; tp<8; tp++){
    const int pp = tp & 1;
    const float* qb  = &qs[(4*tp)*128 + g*32];
    const float* wvr = &wvs[g*32];
    float acc0=0.f, acc1=0.f, acc2=0.f, acc3=0.f;
    #pragma unroll
    for (int mm=0; mm<8; mm++){
      float4 Pv = p4[mm];
      float4 wv = *(const float4*)&wvr[mm*4];
      #pragma unroll
      for (int tl=0; tl<4; tl++){
        float4 qq = *(const float4*)&qb[tl*128 + mm*4];
        float u = fmaf(Pv.x, qq.x, 1.f), v = fmaf(Pv.y, qq.y, 1.f);
        float x = fmaf(Pv.z, qq.z, 1.f), y = fmaf(Pv.w, qq.w, 1.f);
        float d01 = u*v, d23 = x*y;
        float n01 = fmaf(wv.x, v, wv.y*u);
        float n23 = fmaf(wv.z, y, wv.w*x);
        float N = fmaf(n01, d23, n23*d01);
        float r = fast_rcp(d01*d23);
        float term = N*r;
        if (tl==0) acc0 += term;
        else if (tl==1) acc1 += term;
        else if (tl==2) acc2 += term;
        else acc3 += term;
      }
    }
    epart[pp][g][0][i] = acc0;
    epart[pp][g][1][i] = acc1;
    epart[pp][g][2][i] = acc2;
    epart[pp][g][3][i] = acc3;
    __syncthreads();
    // thread handles tl = g for the reduction + output
    float e = epart[pp][0][g][i] + epart[pp][1][g][i]
            + epart[pp][2][g][i] + epart[pp][3][g][i];
    float pe = fast_exp2(e*L2E);
    float sm = pe;
    #pragma unroll
    for (int off=32; off; off>>=1) sm += __shfl_xor(sm, off);
    if ((tid & 63) == 0) red[pp][g][(tid>>6)&1] = sm;
    __syncthreads();
    float ssum = red[pp][g][0] + red[pp][g][1];
    float alpha = pe * fast_rcp(ssum);
    int t = t0 + 4*tp + g;
    int base = (t*512 + b)*128 + i;
    out[base] = data[base]*alpha;
  }
}

extern "C" void kernel_launch(void* const* d_in, const int* in_sizes, int n_in,
                              void* d_out, int out_size, void* d_ws, size_t ws_size,
                              hipStream_t stream) {
  const float* data = (const float*)d_in[0];
  const float* h0   = (const float*)d_in[1];
  const float* Wx   = (const float*)d_in[2];
  const float* Wh   = (const float*)d_in[3];
  const float* bb   = (const float*)d_in[4];
  const float* W1   = (const float*)d_in[5];
  const float* b1   = (const float*)d_in[6];
  const float* W2   = (const float*)d_in[7];
  const float* b2   = (const float*)d_in[8];
  const float* Wv   = (const float*)d_in[9];
  // d_in[10] = bv: softmax-invariant constant, dropped. d_in[11] = n (128).
  float* wsp = (float*)d_ws;
  float* P   = wsp;                         //  8,388,608 f
  float* xwQ = wsp + 8388608;               // 16,777,216 f (xw, then reused as Q)
  hf*    Hbf = (hf*)(wsp + 25165824);       // 16,777,216 hf
  hf*    wts = (hf*)(wsp + 33554432);       // 81,920 hf
  const hf* Wxt = wts;                      // [256][128]
  const hf* W2t = wts + 32768;              // [128][256]
  const hf* W1t = wts + 65536;              // [128][128]
  float* out = (float*)d_out;

  hipLaunchKernelGGL(k_prep_w, dim3(320), dim3(256), 0, stream, Wx, W2, W1, wts);
  hipLaunchKernelGGL((k_gemm<128,0>), dim3(1024,2), dim3(256), 0, stream,
                     (const void*)data, Wxt, bb, xwQ);
  hipLaunchKernelGGL((k_gemm<128,2>), dim3(1024),   dim3(256), 0, stream,
                     (const void*)data, W1t, b1, P);
  hipLaunchKernelGGL(k_rnn, dim3(32), dim3(512), 0, stream, h0, Wh, xwQ, Hbf);
  hipLaunchKernelGGL((k_gemm<256,1>), dim3(1024),   dim3(256), 0, stream,
                     (const void*)Hbf, W2t, b2, xwQ);
  hipLaunchKernelGGL(k_attn, dim3(512, 4), dim3(512), 0, stream, P, xwQ, Wv, data, out);
}

// Round 9
// 367.667 us; speedup vs baseline: 1.1251x; 1.0139x over previous
//
#include <hip/hip_runtime.h>

// Encoder: B=512, T=128, N=128, H=256
// Round 13: k_rnn only (attn/gemm = Round-7/12 proven versions).
//   R12 post-mortem: k_rnn 133.8us with MfmaUtil 2.4 / VALU 6.3 / Occ 2.9%:
//   per-step ~2500cyc of stall. Cause: __syncthreads lowers to
//   s_waitcnt vmcnt(0) lgkmcnt(0) + s_barrier -> every step drained 16
//   scattered 2B Hb stores + the xw prefetch loads (defeating dist-2).
//   Fixes:
//   1. raw barrier (lgkmcnt(0)+s_barrier in one asm) -> no vmcnt drain;
//      xw loads now genuinely span 2 steps; Hb stores fire-and-forget.
//   2. Hb export via LDS readback: 1x ds_read_b128 + 1x dwordx4 store per
//      thread per step (h_{T-1} from the parity buffer), replacing 16
//      scalar stores.
//   3. swizzle SWZ(r)=(r^(r>>2))&7: MFMA row groups {k,4+k,8+k,12+k} now
//      hit 4 distinct slot classes (was 2) -> ds_write conflicts ~free.
// Workspace (f32 offsets): P 0 | xw/Q 8388608 | Hb(hf) 25165824 | wts(hf) 33554432

#define C2L 2.8853900817779268f   // 2*log2(e)
#define L2E 1.4426950408889634f   // log2(e)
#define SWZ(r) (((r) ^ ((r) >> 2)) & 7)

typedef _Float16 hf;
typedef _Float16 hf4 __attribute__((ext_vector_type(4)));
typedef _Float16 hf8 __attribute__((ext_vector_type(8)));
typedef float f32x4 __attribute__((ext_vector_type(4)));

__device__ __forceinline__ float fast_exp2(float x){
#if __has_builtin(__builtin_amdgcn_exp2f)
  return __builtin_amdgcn_exp2f(x);
#else
  return exp2f(x);
#endif
}
__device__ __forceinline__ float fast_rcp(float x){
#if __has_builtin(__builtin_amdgcn_rcpf)
  return __builtin_amdgcn_rcpf(x);
#else
  return 1.f/x;
#endif
}

// ---------------- weight prep: f32 [k][n] -> f16 [n][k] ----------------
__global__ __launch_bounds__(256) void k_prep_w(const float* __restrict__ Wx,
    const float* __restrict__ W2, const float* __restrict__ W1,
    hf* __restrict__ wts){
  int tid = blockIdx.x*256 + threadIdx.x;   // 320 blocks -> 81920 threads
  if (tid < 32768){                          // Wxt[n<256][k<128]
    int n = tid >> 7, k = tid & 127;
    wts[tid] = (hf)Wx[k*256 + n];
  } else if (tid < 65536){                   // W2t[n<128][k<256]
    int t2 = tid - 32768;
    int n = t2 >> 8, k = t2 & 255;
    wts[tid] = (hf)W2[k*128 + n];
  } else {                                   // W1t[n<128][k<128]
    int t3 = tid - 65536;
    int n = t3 >> 7, k = t3 & 127;
    wts[tid] = (hf)W1[k*128 + n];
  }
}

// ---------------- unified MFMA GEMM ----------------
// block = 256 thr (4 waves). Tile: M=64 (wave strip 16), N=128, K chunked by 128.
// LDS: As[64][136] + Bs[128][136] f16 = 52,224 B.
template<int K, int MODE>
__global__ __launch_bounds__(256) void k_gemm(const void* __restrict__ Asrc,
    const hf* __restrict__ Bt, const float* __restrict__ bias,
    float* __restrict__ Cout){
  constexpr int SA = 136;
  __shared__ alignas(16) hf As[64*SA];
  __shared__ alignas(16) hf Bs[128*SA];
  const int tid = threadIdx.x;
  const int w = tid >> 6, lane = tid & 63;
  const int c = lane & 15, q = lane >> 4;
  const int bx = blockIdx.x;
  const int col0 = (MODE==0) ? blockIdx.y*128 : 0;

  float br[8];
  #pragma unroll
  for (int ni=0; ni<8; ni++) br[ni] = bias[col0 + ni*16 + c];

  f32x4 acc[8];
  #pragma unroll
  for (int ni=0; ni<8; ni++) acc[ni] = (f32x4){0.f,0.f,0.f,0.f};

  for (int kc=0; kc<K/128; kc++){
    // ---- stage A chunk (64 rows x 128 k) ----
    if (MODE == 0){
      const float* A = (const float*)Asrc + (long)bx*64*128;
      #pragma unroll
      for (int v=0; v<8; v++){
        int f4 = v*256 + tid;
        int m = f4 >> 5, k4 = (f4 & 31)*4;
        float4 d = *(const float4*)&A[m*128 + k4];
        hf4 h = {(hf)d.x,(hf)d.y,(hf)d.z,(hf)d.w};
        *(hf4*)&As[m*SA + k4] = h;
      }
    } else if (MODE == 1){
      const hf* A = (const hf*)Asrc + (long)bx*64*256;
      #pragma unroll
      for (int v=0; v<4; v++){
        int f8 = v*256 + tid;
        int m = f8 >> 4, k8 = (f8 & 15)*8;
        *(hf8*)&As[m*SA + k8] = *(const hf8*)&A[m*256 + kc*128 + k8];
      }
    } else {
      const float* A = (const float*)Asrc + (long)(bx>>1)*16384;
      const int i0 = (bx & 1)*64;
      #pragma unroll
      for (int v=0; v<8; v++){
        int f4 = v*256 + tid;
        int t = f4 >> 4, i4 = (f4 & 15)*4;
        float4 d = *(const float4*)&A[t*128 + i0 + i4];
        As[(i4+0)*SA + t] = (hf)d.x;
        As[(i4+1)*SA + t] = (hf)d.y;
        As[(i4+2)*SA + t] = (hf)d.z;
        As[(i4+3)*SA + t] = (hf)d.w;
      }
    }
    // ---- stage B chunk (128 n x 128 k), Bt is f16 [n][K] ----
    #pragma unroll
    for (int v=0; v<8; v++){
      int f8 = v*256 + tid;
      int n = f8 >> 4, k8 = (f8 & 15)*8;
      *(hf8*)&Bs[n*SA + k8] = *(const hf8*)&Bt[(col0+n)*K + kc*128 + k8];
    }
    __syncthreads();
    // ---- MFMA ----
    #pragma unroll
    for (int kk=0; kk<4; kk++){
      hf8 a = *(const hf8*)&As[(w*16 + c)*SA + kk*32 + q*8];
      #pragma unroll
      for (int ni=0; ni<8; ni++){
        hf8 b = *(const hf8*)&Bs[(ni*16 + c)*SA + kk*32 + q*8];
        acc[ni] = __builtin_amdgcn_mfma_f32_16x16x32_f16(a, b, acc[ni], 0, 0, 0);
      }
    }
    __syncthreads();
  }
  // ---- epilogue ----
  #pragma unroll
  for (int ni=0; ni<8; ni++){
    #pragma unroll
    for (int r=0; r<4; r++){
      int rloc = w*16 + q*4 + r;
      int col = col0 + ni*16 + c;
      float val = acc[ni][r] + br[ni];
      int addr;
      if (MODE == 0){
        int R = bx*64 + rloc;
        int b_ = R >> 7, t_ = R & 127;
        addr = (t_*512 + b_)*256 + col;
      } else if (MODE == 1){
        int R = bx*64 + rloc;
        addr = R*128 + col;
        val = fast_exp2(C2L*val);
      } else {
        int b_ = bx >> 1, i_ = (bx & 1)*64 + rloc;
        addr = b_*16384 + i_*128 + col;
        val = fast_exp2(C2L*val);
      }
      Cout[addr] = val;
    }
  }
}

// ---------------- recurrence (MFMA, 8 waves, raw barrier) ----------------
// 32 blocks x 512 thr. Block owns batches [16*bx,16*bx+16); wave w owns cols
// [32w,32w+32): 2 n-tiles fed by shared a-frags. h[16][256] hf ping-pongs in
// LDS with SWZ slot-swizzle. Per step: export h_{T-1} (1 ds_read_b128 +
// 1 global_store_dwordx4 / thread), a-frags, 4x4-deep MFMA, dist-2 xw
// reload, paired-rcp tanh, swizzled ds_write, raw lgkm-only barrier
// (global traffic is never drained inside the loop).
__global__ __launch_bounds__(512, 2) void k_rnn(const float* __restrict__ h0,
    const float* __restrict__ Wh, const float* __restrict__ xw,
    hf* __restrict__ Hb){
  __shared__ alignas(16) char hs[2*8192];   // [parity][16 rows x 512B]
  const int tid = threadIdx.x;
  const int w = tid >> 6, lane = tid & 63;
  const int c = lane & 15, q = lane >> 4;
  const int b0 = blockIdx.x * 16;
  const int w0 = w * 32;
  const int me = tid >> 5, se = tid & 31;    // export row / 16B slot
  // ---- Wh B-frags: bw[nt][kc][e] = Wh[kc*32+q*8+e][w0+nt*16+c] ----
  hf8 bw[2][8];
  #pragma unroll
  for (int nt=0; nt<2; nt++){
    #pragma unroll
    for (int kc=0; kc<8; kc++){
      #pragma unroll
      for (int e=0; e<8; e++){
        bw[nt][kc][e] = (hf)Wh[(kc*32 + q*8 + e)*256 + w0 + nt*16 + c];
      }
    }
  }
  // ---- stage h0 -> hs[parity 0], swizzled ----
  {
    const float* src = &h0[(b0 + me)*256 + se*8];
    float4 d0 = *(const float4*)&src[0];
    float4 d1 = *(const float4*)&src[4];
    hf8 hv = {(hf)d0.x,(hf)d0.y,(hf)d0.z,(hf)d0.w,
              (hf)d1.x,(hf)d1.y,(hf)d1.z,(hf)d1.w};
    *(hf8*)&hs[me*512 + ((se ^ SWZ(me)) << 4)] = hv;
  }
  // ---- prologue: xw for t=0 (bufA) and t=1 (bufB) ----
  float bufA[2][4], bufB[2][4];
  #pragma unroll
  for (int nt=0; nt<2; nt++){
    #pragma unroll
    for (int r=0; r<4; r++){
      bufA[nt][r] = xw[(0*512 + b0 + q*4 + r)*256 + w0 + nt*16 + c];
      bufB[nt][r] = xw[(1*512 + b0 + q*4 + r)*256 + w0 + nt*16 + c];
    }
  }
  __syncthreads();
  #pragma unroll 1
  for (int t=0; t<128; t+=2){
    #pragma unroll
    for (int half=0; half<2; half++){
      const int T = t + half;
      const int p = T & 1;
      // ---- export h_{T-1} from parity p (linear readback, wide store) ----
      if (T > 0){
        hf8 ex = *(const hf8*)&hs[p*8192 + me*512 + ((se ^ SWZ(me)) << 4)];
        *(hf8*)&Hb[((T-1)*512 + b0 + me)*256 + se*8] = ex;
      }
      // ---- A-frags from LDS (swizzled, conflict-free) ----
      hf8 a[8];
      #pragma unroll
      for (int kc=0; kc<8; kc++)
        a[kc] = *(const hf8*)&hs[p*8192 + c*512
                                 + ((((kc<<2)|q) ^ SWZ(c)) << 4)];
      // ---- 4 independent 4-deep MFMA chains (a shared across n-tiles) ----
      f32x4 ac0a = (f32x4){0.f,0.f,0.f,0.f}, ac0b = ac0a;
      f32x4 ac1a = ac0a, ac1b = ac0a;
      #pragma unroll
      for (int kc=0; kc<4; kc++){
        ac0a = __builtin_amdgcn_mfma_f32_16x16x32_f16(a[kc],   bw[0][kc],   ac0a,0,0,0);
        ac1a = __builtin_amdgcn_mfma_f32_16x16x32_f16(a[kc],   bw[1][kc],   ac1a,0,0,0);
        ac0b = __builtin_amdgcn_mfma_f32_16x16x32_f16(a[kc+4], bw[0][kc+4], ac0b,0,0,0);
        ac1b = __builtin_amdgcn_mfma_f32_16x16x32_f16(a[kc+4], bw[1][kc+4], ac1b,0,0,0);
      }
      // ---- consume buf -> vv; immediately reload buf for T+2 ----
      float vv[2][4];
      #pragma unroll
      for (int r=0; r<4; r++){
        vv[0][r] = ac0a[r] + ac0b[r] + (half ? bufB[0][r] : bufA[0][r]);
        vv[1][r] = ac1a[r] + ac1b[r] + (half ? bufB[1][r] : bufA[1][r]);
      }
      #pragma unroll
      for (int nt=0; nt<2; nt++){
        #pragma unroll
        for (int r=0; r<4; r++){
          float nv = (T+2 < 128)
            ? xw[((T+2)*512 + b0 + q*4 + r)*256 + w0 + nt*16 + c] : 0.f;
          if (half) bufB[nt][r] = nv; else bufA[nt][r] = nv;
        }
      }
      // ---- tanh (paired rcp) + swizzled LDS writes (parity p^1) ----
      #pragma unroll
      for (int nt=0; nt<2; nt++){
        #pragma unroll
        for (int pr=0; pr<2; pr++){
          float ea = fast_exp2(vv[nt][2*pr+0]*C2L) + 1.f;
          float eb = fast_exp2(vv[nt][2*pr+1]*C2L) + 1.f;
          float R = fast_rcp(ea*eb);
          float h0v = fmaf(-2.f*eb, R, 1.f);
          float h1v = fmaf(-2.f*ea, R, 1.f);
          #pragma unroll
          for (int rr=0; rr<2; rr++){
            float hn = rr ? h1v : h0v;
            int row = q*4 + 2*pr + rr;
            int col = w0 + nt*16 + c;
            *(hf*)&hs[(p^1)*8192 + row*512
                      + (((col >> 3) ^ SWZ(row)) << 4) + (col & 7)*2] = (hf)hn;
          }
        }
      }
      // ---- raw barrier: LDS ordering only, no vmcnt drain ----
      asm volatile("s_waitcnt lgkmcnt(0)\n\ts_barrier" ::: "memory");
    }
  }
  // ---- final export: h_127 lives in parity 0 ----
  {
    hf8 ex = *(const hf8*)&hs[me*512 + ((se ^ SWZ(me)) << 4)];
    *(hf8*)&Hb[(127*512 + b0 + me)*256 + se*8] = ex;
  }
}

// ---------------- attention + softmax + scale ----------------
// grid (512 b, 4 t-tiles), 512 threads. Thread = (i, tau-quarter g of 32).
// P quarter in registers (8 float4 = 32 VGPR). Q tile (32 t) in LDS.
// 4-way rcp: w0/u+w1/v+w2/x+w3/y = (n01*d23+n23*d01)*rcp(d01*d23)
// -> 1 rcp per 4 taus. 4 timesteps per sweep; 2 barriers per sweep.
// No max in softmax (|e| <= sum|wv| ~ 5).
__global__ __launch_bounds__(512, 4) void k_attn(const float* __restrict__ P,
    const float* __restrict__ Qm, const float* __restrict__ Wv,
    const float* __restrict__ data, float* __restrict__ out){
  __shared__ alignas(16) float qs[32*128];          // [tt][tau] 16KB
  __shared__ alignas(16) float wvs[128];
  __shared__ alignas(16) float epart[2][4][4][128]; // [parity][quar][tl][i] 16KB
  __shared__ float red[2][4][2];                    // [parity][tl][half]
  const int b = blockIdx.x, tile = blockIdx.y;
  const int tid = threadIdx.x;
  const int i = tid & 127, g = tid >> 7;            // i, tau-quarter 0..3
  const int t0 = tile*32;
  if (tid < 128) wvs[tid] = -2.f*Wv[tid];
  #pragma unroll
  for (int v=0; v<2; v++){
    int flat = v*2048 + tid*4;
    int tt = flat >> 7, c = flat & 127;
    *(float4*)&qs[flat] = *(const float4*)&Qm[((t0+tt)*512 + b)*128 + c];
  }
  float4 p4[8];
  const float* prow = P + b*16384 + i*128 + g*32;
  #pragma unroll
  for (int v=0; v<8; v++) p4[v] = *(const float4*)&prow[v*4];
  __syncthreads();
  for (int tp=0; tp<8; tp++){
    const int pp = tp & 1;
    const float* qb  = &qs[(4*tp)*128 + g*32];
    const float* wvr = &wvs[g*32];
    float acc0=0.f, acc1=0.f, acc2=0.f, acc3=0.f;
    #pragma unroll
    for (int mm=0; mm<8; mm++){
      float4 Pv = p4[mm];
      float4 wv = *(const float4*)&wvr[mm*4];
      #pragma unroll
      for (int tl=0; tl<4; tl++){
        float4 qq = *(const float4*)&qb[tl*128 + mm*4];
        float u = fmaf(Pv.x, qq.x, 1.f), v = fmaf(Pv.y, qq.y, 1.f);
        float x = fmaf(Pv.z, qq.z, 1.f), y = fmaf(Pv.w, qq.w, 1.f);
        float d01 = u*v, d23 = x*y;
        float n01 = fmaf(wv.x, v, wv.y*u);
        float n23 = fmaf(wv.z, y, wv.w*x);
        float N = fmaf(n01, d23, n23*d01);
        float r = fast_rcp(d01*d23);
        float term = N*r;
        if (tl==0) acc0 += term;
        else if (tl==1) acc1 += term;
        else if (tl==2) acc2 += term;
        else acc3 += term;
      }
    }
    epart[pp][g][0][i] = acc0;
    epart[pp][g][1][i] = acc1;
    epart[pp][g][2][i] = acc2;
    epart[pp][g][3][i] = acc3;
    __syncthreads();
    // thread handles tl = g for the reduction + output
    float e = epart[pp][0][g][i] + epart[pp][1][g][i]
            + epart[pp][2][g][i] + epart[pp][3][g][i];
    float pe = fast_exp2(e*L2E);
    float sm = pe;
    #pragma unroll
    for (int off=32; off; off>>=1) sm += __shfl_xor(sm, off);
    if ((tid & 63) == 0) red[pp][g][(tid>>6)&1] = sm;
    __syncthreads();
    float ssum = red[pp][g][0] + red[pp][g][1];
    float alpha = pe * fast_rcp(ssum);
    int t = t0 + 4*tp + g;
    int base = (t*512 + b)*128 + i;
    out[base] = data[base]*alpha;
  }
}

extern "C" void kernel_launch(void* const* d_in, const int* in_sizes, int n_in,
                              void* d_out, int out_size, void* d_ws, size_t ws_size,
                              hipStream_t stream) {
  const float* data = (const float*)d_in[0];
  const float* h0   = (const float*)d_in[1];
  const float* Wx   = (const float*)d_in[2];
  const float* Wh   = (const float*)d_in[3];
  const float* bb   = (const float*)d_in[4];
  const float* W1   = (const float*)d_in[5];
  const float* b1   = (const float*)d_in[6];
  const float* W2   = (const float*)d_in[7];
  const float* b2   = (const float*)d_in[8];
  const float* Wv   = (const float*)d_in[9];
  // d_in[10] = bv: softmax-invariant constant, dropped. d_in[11] = n (128).
  float* wsp = (float*)d_ws;
  float* P   = wsp;                         //  8,388,608 f
  float* xwQ = wsp + 8388608;               // 16,777,216 f (xw, then reused as Q)
  hf*    Hbf = (hf*)(wsp + 25165824);       // 16,777,216 hf
  hf*    wts = (hf*)(wsp + 33554432);       // 81,920 hf
  const hf* Wxt = wts;                      // [256][128]
  const hf* W2t = wts + 32768;              // [128][256]
  const hf* W1t = wts + 65536;              // [128][128]
  float* out = (float*)d_out;

  hipLaunchKernelGGL(k_prep_w, dim3(320), dim3(256), 0, stream, Wx, W2, W1, wts);
  hipLaunchKernelGGL((k_gemm<128,0>), dim3(1024,2), dim3(256), 0, stream,
                     (const void*)data, Wxt, bb, xwQ);
  hipLaunchKernelGGL((k_gemm<128,2>), dim3(1024),   dim3(256), 0, stream,
                     (const void*)data, W1t, b1, P);
  hipLaunchKernelGGL(k_rnn, dim3(32), dim3(512), 0, stream, h0, Wh, xwQ, Hbf);
  hipLaunchKernelGGL((k_gemm<256,1>), dim3(1024),   dim3(256), 0, stream,
                     (const void*)Hbf, W2t, b2, xwQ);
  hipLaunchKernelGGL(k_attn, dim3(512, 4), dim3(512), 0, stream, P, xwQ, Wv, data, out);
}

// Round 10
// 357.865 us; speedup vs baseline: 1.1559x; 1.0274x over previous
//
#include <hip/hip_runtime.h>

// Encoder: B=512, T=128, N=128, H=256
// Round 14: k_rnn operand-swap (attn/gemm/prep byte-identical to R13 keepers).
//   R13 post-mortem: k_rnn is LDS-PIPE-bound: 8 waves x (8 ds_read_b128 +
//   export) + 64 scalar 2B ds_writes = ~144 LDS instr = ~1600cyc/step.
//   Fix: compute D = Wh^T (A) x h^T (B) instead of h x Wh. D lane map becomes
//   [oc=4q+r][batch=c]: 4 consecutive out-cols per lane ->
//   - h-update: 1 packed ds_write_b64 per n-tile (2/thread, was 8 scalar b16)
//   - Hb export: direct hf4 register store (LDS readback deleted)
//   - xw add: float4 load per n-tile (was 4 scalar)
//   B-frag h reads are byte-identical to the old A-frag reads (same swizzle,
//   2-way-free); weight VGPRs hold the same values (now as A operand).
//   LDS instr/CU/step: 144 -> 80. Raw lgkm-only barrier kept (1/step).
// Workspace (f32 offsets): P 0 | xw/Q 8388608 | Hb(hf) 25165824 | wts(hf) 33554432

#define C2L 2.8853900817779268f   // 2*log2(e)
#define L2E 1.4426950408889634f   // log2(e)

typedef _Float16 hf;
typedef _Float16 hf4 __attribute__((ext_vector_type(4)));
typedef _Float16 hf8 __attribute__((ext_vector_type(8)));
typedef float f32x4 __attribute__((ext_vector_type(4)));

__device__ __forceinline__ float fast_exp2(float x){
#if __has_builtin(__builtin_amdgcn_exp2f)
  return __builtin_amdgcn_exp2f(x);
#else
  return exp2f(x);
#endif
}
__device__ __forceinline__ float fast_rcp(float x){
#if __has_builtin(__builtin_amdgcn_rcpf)
  return __builtin_amdgcn_rcpf(x);
#else
  return 1.f/x;
#endif
}

// ---------------- weight prep: f32 [k][n] -> f16 [n][k] ----------------
__global__ __launch_bounds__(256) void k_prep_w(const float* __restrict__ Wx,
    const float* __restrict__ W2, const float* __restrict__ W1,
    hf* __restrict__ wts){
  int tid = blockIdx.x*256 + threadIdx.x;   // 320 blocks -> 81920 threads
  if (tid < 32768){                          // Wxt[n<256][k<128]
    int n = tid >> 7, k = tid & 127;
    wts[tid] = (hf)Wx[k*256 + n];
  } else if (tid < 65536){                   // W2t[n<128][k<256]
    int t2 = tid - 32768;
    int n = t2 >> 8, k = t2 & 255;
    wts[tid] = (hf)W2[k*128 + n];
  } else {                                   // W1t[n<128][k<128]
    int t3 = tid - 65536;
    int n = t3 >> 7, k = t3 & 127;
    wts[tid] = (hf)W1[k*128 + n];
  }
}

// ---------------- unified MFMA GEMM ----------------
// block = 256 thr (4 waves). Tile: M=64 (wave strip 16), N=128, K chunked by 128.
// LDS: As[64][136] + Bs[128][136] f16 = 52,224 B.
template<int K, int MODE>
__global__ __launch_bounds__(256) void k_gemm(const void* __restrict__ Asrc,
    const hf* __restrict__ Bt, const float* __restrict__ bias,
    float* __restrict__ Cout){
  constexpr int SA = 136;
  __shared__ alignas(16) hf As[64*SA];
  __shared__ alignas(16) hf Bs[128*SA];
  const int tid = threadIdx.x;
  const int w = tid >> 6, lane = tid & 63;
  const int c = lane & 15, q = lane >> 4;
  const int bx = blockIdx.x;
  const int col0 = (MODE==0) ? blockIdx.y*128 : 0;

  float br[8];
  #pragma unroll
  for (int ni=0; ni<8; ni++) br[ni] = bias[col0 + ni*16 + c];

  f32x4 acc[8];
  #pragma unroll
  for (int ni=0; ni<8; ni++) acc[ni] = (f32x4){0.f,0.f,0.f,0.f};

  for (int kc=0; kc<K/128; kc++){
    // ---- stage A chunk (64 rows x 128 k) ----
    if (MODE == 0){
      const float* A = (const float*)Asrc + (long)bx*64*128;
      #pragma unroll
      for (int v=0; v<8; v++){
        int f4 = v*256 + tid;
        int m = f4 >> 5, k4 = (f4 & 31)*4;
        float4 d = *(const float4*)&A[m*128 + k4];
        hf4 h = {(hf)d.x,(hf)d.y,(hf)d.z,(hf)d.w};
        *(hf4*)&As[m*SA + k4] = h;
      }
    } else if (MODE == 1){
      const hf* A = (const hf*)Asrc + (long)bx*64*256;
      #pragma unroll
      for (int v=0; v<4; v++){
        int f8 = v*256 + tid;
        int m = f8 >> 4, k8 = (f8 & 15)*8;
        *(hf8*)&As[m*SA + k8] = *(const hf8*)&A[m*256 + kc*128 + k8];
      }
    } else {
      const float* A = (const float*)Asrc + (long)(bx>>1)*16384;
      const int i0 = (bx & 1)*64;
      #pragma unroll
      for (int v=0; v<8; v++){
        int f4 = v*256 + tid;
        int t = f4 >> 4, i4 = (f4 & 15)*4;
        float4 d = *(const float4*)&A[t*128 + i0 + i4];
        As[(i4+0)*SA + t] = (hf)d.x;
        As[(i4+1)*SA + t] = (hf)d.y;
        As[(i4+2)*SA + t] = (hf)d.z;
        As[(i4+3)*SA + t] = (hf)d.w;
      }
    }
    // ---- stage B chunk (128 n x 128 k), Bt is f16 [n][K] ----
    #pragma unroll
    for (int v=0; v<8; v++){
      int f8 = v*256 + tid;
      int n = f8 >> 4, k8 = (f8 & 15)*8;
      *(hf8*)&Bs[n*SA + k8] = *(const hf8*)&Bt[(col0+n)*K + kc*128 + k8];
    }
    __syncthreads();
    // ---- MFMA ----
    #pragma unroll
    for (int kk=0; kk<4; kk++){
      hf8 a = *(const hf8*)&As[(w*16 + c)*SA + kk*32 + q*8];
      #pragma unroll
      for (int ni=0; ni<8; ni++){
        hf8 b = *(const hf8*)&Bs[(ni*16 + c)*SA + kk*32 + q*8];
        acc[ni] = __builtin_amdgcn_mfma_f32_16x16x32_f16(a, b, acc[ni], 0, 0, 0);
      }
    }
    __syncthreads();
  }
  // ---- epilogue ----
  #pragma unroll
  for (int ni=0; ni<8; ni++){
    #pragma unroll
    for (int r=0; r<4; r++){
      int rloc = w*16 + q*4 + r;
      int col = col0 + ni*16 + c;
      float val = acc[ni][r] + br[ni];
      int addr;
      if (MODE == 0){
        int R = bx*64 + rloc;
        int b_ = R >> 7, t_ = R & 127;
        addr = (t_*512 + b_)*256 + col;
      } else if (MODE == 1){
        int R = bx*64 + rloc;
        addr = R*128 + col;
        val = fast_exp2(C2L*val);
      } else {
        int b_ = bx >> 1, i_ = (bx & 1)*64 + rloc;
        addr = b_*16384 + i_*128 + col;
        val = fast_exp2(C2L*val);
      }
      Cout[addr] = val;
    }
  }
}

// ---------------- recurrence (MFMA, operand-swapped) ----------------
// 32 blocks x 512 thr (8 waves). Block owns batches [16*bx,16*bx+16); wave w
// owns out-cols [32w,32w+32) (2 n-tiles). D = Wh^T (A, in VGPRs) x h^T (B,
// from LDS). Lane (c,q) of n-tile nt gets D[oc=w0+nt*16+4q+r][batch=c]:
// 4 consecutive out-cols -> packed hf4 LDS write + direct hf4 Hb export +
// float4 xw add. h[16 batches][256 hcol] hf in LDS, slot-swizzle
// slot^= (batch&7) (element k at batch*512 + ((k>>3 ^ (batch&7))<<4) +
// (k&7)*2): B-frag reads AND packed writes both 2-way max (free).
// dist-2 xw prefetch; raw lgkm-only barrier, 1/step.
__global__ __launch_bounds__(512, 2) void k_rnn(const float* __restrict__ h0,
    const float* __restrict__ Wh, const float* __restrict__ xw,
    hf* __restrict__ Hb){
  __shared__ alignas(16) char hs[2*8192];   // [parity][16 batches x 512B]
  const int tid = threadIdx.x;
  const int w = tid >> 6, lane = tid & 63;
  const int c = lane & 15, q = lane >> 4;
  const int b0 = blockIdx.x * 16;
  const int w0 = w * 32;
  const int oc0 = w0 + 4*q;                  // n-tile nt adds +16
  // ---- Wh as A-frags: aw[nt][kc][e] = Wh[kc*32+q*8+e][w0+nt*16+c] ----
  hf8 aw[2][8];
  #pragma unroll
  for (int nt=0; nt<2; nt++){
    #pragma unroll
    for (int kc=0; kc<8; kc++){
      #pragma unroll
      for (int e=0; e<8; e++){
        aw[nt][kc][e] = (hf)Wh[(kc*32 + q*8 + e)*256 + w0 + nt*16 + c];
      }
    }
  }
  // ---- stage h0 -> hs[parity 0], swizzled [batch][hcol] ----
  {
    int m = tid >> 5, s8 = tid & 31;         // batch row, 16B slot
    const float* src = &h0[(b0 + m)*256 + s8*8];
    float4 d0 = *(const float4*)&src[0];
    float4 d1 = *(const float4*)&src[4];
    hf8 hv = {(hf)d0.x,(hf)d0.y,(hf)d0.z,(hf)d0.w,
              (hf)d1.x,(hf)d1.y,(hf)d1.z,(hf)d1.w};
    *(hf8*)&hs[m*512 + ((s8 ^ (m & 7)) << 4)] = hv;
  }
  // ---- prologue: xw for t=0 (xA) and t=1 (xB), float4 per n-tile ----
  float4 xA[2], xB[2];
  #pragma unroll
  for (int nt=0; nt<2; nt++){
    xA[nt] = *(const float4*)&xw[(0*512 + b0 + c)*256 + oc0 + nt*16];
    xB[nt] = *(const float4*)&xw[(1*512 + b0 + c)*256 + oc0 + nt*16];
  }
  __syncthreads();
  #pragma unroll 1
  for (int t=0; t<128; t+=2){
    #pragma unroll
    for (int half=0; half<2; half++){
      const int T = t + half;
      const int p = T & 1;
      // ---- h B-frags from LDS (swizzled, 2-way free) ----
      hf8 hb[8];
      #pragma unroll
      for (int kc=0; kc<8; kc++)
        hb[kc] = *(const hf8*)&hs[p*8192 + c*512
                                  + ((((kc<<2)|q) ^ (c & 7)) << 4)];
      // ---- 4 independent 4-deep MFMA chains: D = Wh^T x h^T ----
      f32x4 a0l = (f32x4){0.f,0.f,0.f,0.f}, a0h = a0l;
      f32x4 a1l = a0l, a1h = a0l;
      #pragma unroll
      for (int kc=0; kc<4; kc++){
        a0l = __builtin_amdgcn_mfma_f32_16x16x32_f16(aw[0][kc],   hb[kc],   a0l,0,0,0);
        a1l = __builtin_amdgcn_mfma_f32_16x16x32_f16(aw[1][kc],   hb[kc],   a1l,0,0,0);
        a0h = __builtin_amdgcn_mfma_f32_16x16x32_f16(aw[0][kc+4], hb[kc+4], a0h,0,0,0);
        a1h = __builtin_amdgcn_mfma_f32_16x16x32_f16(aw[1][kc+4], hb[kc+4], a1h,0,0,0);
      }
      // ---- reload xw for T+2 (consumed 2 steps later) ----
      float4 nv[2];
      #pragma unroll
      for (int nt=0; nt<2; nt++){
        nv[nt] = (T+2 < 128)
          ? *(const float4*)&xw[((T+2)*512 + b0 + c)*256 + oc0 + nt*16]
          : (float4){0.f,0.f,0.f,0.f};
      }
      // ---- tanh (paired rcp) + packed LDS write + direct Hb export ----
      #pragma unroll
      for (int nt=0; nt<2; nt++){
        float4 xv = half ? xB[nt] : xA[nt];
        f32x4 al = nt ? a1l : a0l;
        f32x4 ah = nt ? a1h : a0h;
        float v0 = al[0] + ah[0] + xv.x;
        float v1 = al[1] + ah[1] + xv.y;
        float v2 = al[2] + ah[2] + xv.z;
        float v3 = al[3] + ah[3] + xv.w;
        float ea = fast_exp2(v0*C2L) + 1.f;
        float eb = fast_exp2(v1*C2L) + 1.f;
        float R0 = fast_rcp(ea*eb);
        float ec = fast_exp2(v2*C2L) + 1.f;
        float ed = fast_exp2(v3*C2L) + 1.f;
        float R1 = fast_rcp(ec*ed);
        hf4 h4 = {(hf)fmaf(-2.f*eb, R0, 1.f), (hf)fmaf(-2.f*ea, R0, 1.f),
                  (hf)fmaf(-2.f*ed, R1, 1.f), (hf)fmaf(-2.f*ec, R1, 1.f)};
        const int k0 = oc0 + nt*16;          // 4-aligned -> stays in one slot
        *(hf4*)&hs[(p^1)*8192 + c*512
                   + (((k0 >> 3) ^ (c & 7)) << 4) + (k0 & 7)*2] = h4;
        *(hf4*)&Hb[(T*512 + b0 + c)*256 + k0] = h4;
        if (half) xB[nt] = nv[nt]; else xA[nt] = nv[nt];
      }
      // ---- raw barrier: LDS ordering only, no vmcnt drain ----
      asm volatile("s_waitcnt lgkmcnt(0)\n\ts_barrier" ::: "memory");
    }
  }
}

// ---------------- attention + softmax + scale ----------------
// grid (512 b, 4 t-tiles), 512 threads. Thread = (i, tau-quarter g of 32).
// P quarter in registers (8 float4 = 32 VGPR). Q tile (32 t) in LDS.
// 4-way rcp: w0/u+w1/v+w2/x+w3/y = (n01*d23+n23*d01)*rcp(d01*d23)
// -> 1 rcp per 4 taus. 4 timesteps per sweep; 2 barriers per sweep.
// No max in softmax (|e| <= sum|wv| ~ 5).
__global__ __launch_bounds__(512, 4) void k_attn(const float* __restrict__ P,
    const float* __restrict__ Qm, const float* __restrict__ Wv,
    const float* __restrict__ data, float* __restrict__ out){
  __shared__ alignas(16) float qs[32*128];          // [tt][tau] 16KB
  __shared__ alignas(16) float wvs[128];
  __shared__ alignas(16) float epart[2][4][4][128]; // [parity][quar][tl][i] 16KB
  __shared__ float red[2][4][2];                    // [parity][tl][half]
  const int b = blockIdx.x, tile = blockIdx.y;
  const int tid = threadIdx.x;
  const int i = tid & 127, g = tid >> 7;            // i, tau-quarter 0..3
  const int t0 = tile*32;
  if (tid < 128) wvs[tid] = -2.f*Wv[tid];
  #pragma unroll
  for (int v=0; v<2; v++){
    int flat = v*2048 + tid*4;
    int tt = flat >> 7, c = flat & 127;
    *(float4*)&qs[flat] = *(const float4*)&Qm[((t0+tt)*512 + b)*128 + c];
  }
  float4 p4[8];
  const float* prow = P + b*16384 + i*128 + g*32;
  #pragma unroll
  for (int v=0; v<8; v++) p4[v] = *(const float4*)&prow[v*4];
  __syncthreads();
  for (int tp=0; tp<8; tp++){
    const int pp = tp & 1;
    const float* qb  = &qs[(4*tp)*128 + g*32];
    const float* wvr = &wvs[g*32];
    float acc0=0.f, acc1=0.f, acc2=0.f, acc3=0.f;
    #pragma unroll
    for (int mm=0; mm<8; mm++){
      float4 Pv = p4[mm];
      float4 wv = *(const float4*)&wvr[mm*4];
      #pragma unroll
      for (int tl=0; tl<4; tl++){
        float4 qq = *(const float4*)&qb[tl*128 + mm*4];
        float u = fmaf(Pv.x, qq.x, 1.f), v = fmaf(Pv.y, qq.y, 1.f);
        float x = fmaf(Pv.z, qq.z, 1.f), y = fmaf(Pv.w, qq.w, 1.f);
        float d01 = u*v, d23 = x*y;
        float n01 = fmaf(wv.x, v, wv.y*u);
        float n23 = fmaf(wv.z, y, wv.w*x);
        float N = fmaf(n01, d23, n23*d01);
        float r = fast_rcp(d01*d23);
        float term = N*r;
        if (tl==0) acc0 += term;
        else if (tl==1) acc1 += term;
        else if (tl==2) acc2 += term;
        else acc3 += term;
      }
    }
    epart[pp][g][0][i] = acc0;
    epart[pp][g][1][i] = acc1;
    epart[pp][g][2][i] = acc2;
    epart[pp][g][3][i] = acc3;
    __syncthreads();
    // thread handles tl = g for the reduction + output
    float e = epart[pp][0][g][i] + epart[pp][1][g][i]
            + epart[pp][2][g][i] + epart[pp][3][g][i];
    float pe = fast_exp2(e*L2E);
    float sm = pe;
    #pragma unroll
    for (int off=32; off; off>>=1) sm += __shfl_xor(sm, off);
    if ((tid & 63) == 0) red[pp][g][(tid>>6)&1] = sm;
    __syncthreads();
    float ssum = red[pp][g][0] + red[pp][g][1];
    float alpha = pe * fast_rcp(ssum);
    int t = t0 + 4*tp + g;
    int base = (t*512 + b)*128 + i;
    out[base] = data[base]*alpha;
  }
}

extern "C" void kernel_launch(void* const* d_in, const int* in_sizes, int n_in,
                              void* d_out, int out_size, void* d_ws, size_t ws_size,
                              hipStream_t stream) {
  const float* data = (const float*)d_in[0];
  const float* h0   = (const float*)d_in[1];
  const float* Wx   = (const float*)d_in[2];
  const float* Wh   = (const float*)d_in[3];
  const float* bb   = (const float*)d_in[4];
  const float* W1   = (const float*)d_in[5];
  const float* b1   = (const float*)d_in[6];
  const float* W2   = (const float*)d_in[7];
  const float* b2   = (const float*)d_in[8];
  const float* Wv   = (const float*)d_in[9];
  // d_in[10] = bv: softmax-invariant constant, dropped. d_in[11] = n (128).
  float* wsp = (float*)d_ws;
  float* P   = wsp;                         //  8,388,608 f
  float* xwQ = wsp + 8388608;               // 16,777,216 f (xw, then reused as Q)
  hf*    Hbf = (hf*)(wsp + 25165824);       // 16,777,216 hf
  hf*    wts = (hf*)(wsp + 33554432);       // 81,920 hf
  const hf* Wxt = wts;                      // [256][128]
  const hf* W2t = wts + 32768;              // [128][256]
  const hf* W1t = wts + 65536;              // [128][128]
  float* out = (float*)d_out;

  hipLaunchKernelGGL(k_prep_w, dim3(320), dim3(256), 0, stream, Wx, W2, W1, wts);
  hipLaunchKernelGGL((k_gemm<128,0>), dim3(1024,2), dim3(256), 0, stream,
                     (const void*)data, Wxt, bb, xwQ);
  hipLaunchKernelGGL((k_gemm<128,2>), dim3(1024),   dim3(256), 0, stream,
                     (const void*)data, W1t, b1, P);
  hipLaunchKernelGGL(k_rnn, dim3(32), dim3(512), 0, stream, h0, Wh, xwQ, Hbf);
  hipLaunchKernelGGL((k_gemm<256,1>), dim3(1024),   dim3(256), 0, stream,
                     (const void*)Hbf, W2t, b2, xwQ);
  hipLaunchKernelGGL(k_attn, dim3(512, 4), dim3(512), 0, stream, P, xwQ, Wv, data, out);
}

// Round 11
// 336.885 us; speedup vs baseline: 1.2279x; 1.0623x over previous
//
#include <hip/hip_runtime.h>

// Encoder: B=512, T=128, N=128, H=256
// Round 15: k_rnn = best-of-ledger recombination (attn/gemm/prep untouched).
//   Ledger: 16-wave R7 rnn ~115us beat all 8-wave rewrites (118-134) ->
//   waves/SIMD (4 vs 2) is the dominant lever (latency interleave), not LDS
//   instruction count. This round: 16 waves (1024 thr) + R14 operand-swap
//   (D = Wh^T x h^T: packed hf4 LDS write + direct hf4 Hb export + float4 xw)
//   + R13 raw lgkm-only barrier + dist-2 xw prefetch.
//   Wave w owns out-cols [16w,16w+16): aw 32 VGPR, hb 32, total ~110 < 128
//   (launch_bounds(1024,4)).
// Workspace (f32 offsets): P 0 | xw/Q 8388608 | Hb(hf) 25165824 | wts(hf) 33554432

#define C2L 2.8853900817779268f   // 2*log2(e)
#define L2E 1.4426950408889634f   // log2(e)

typedef _Float16 hf;
typedef _Float16 hf4 __attribute__((ext_vector_type(4)));
typedef _Float16 hf8 __attribute__((ext_vector_type(8)));
typedef float f32x4 __attribute__((ext_vector_type(4)));

__device__ __forceinline__ float fast_exp2(float x){
#if __has_builtin(__builtin_amdgcn_exp2f)
  return __builtin_amdgcn_exp2f(x);
#else
  return exp2f(x);
#endif
}
__device__ __forceinline__ float fast_rcp(float x){
#if __has_builtin(__builtin_amdgcn_rcpf)
  return __builtin_amdgcn_rcpf(x);
#else
  return 1.f/x;
#endif
}

// ---------------- weight prep: f32 [k][n] -> f16 [n][k] ----------------
__global__ __launch_bounds__(256) void k_prep_w(const float* __restrict__ Wx,
    const float* __restrict__ W2, const float* __restrict__ W1,
    hf* __restrict__ wts){
  int tid = blockIdx.x*256 + threadIdx.x;   // 320 blocks -> 81920 threads
  if (tid < 32768){                          // Wxt[n<256][k<128]
    int n = tid >> 7, k = tid & 127;
    wts[tid] = (hf)Wx[k*256 + n];
  } else if (tid < 65536){                   // W2t[n<128][k<256]
    int t2 = tid - 32768;
    int n = t2 >> 8, k = t2 & 255;
    wts[tid] = (hf)W2[k*128 + n];
  } else {                                   // W1t[n<128][k<128]
    int t3 = tid - 65536;
    int n = t3 >> 7, k = t3 & 127;
    wts[tid] = (hf)W1[k*128 + n];
  }
}

// ---------------- unified MFMA GEMM ----------------
// block = 256 thr (4 waves). Tile: M=64 (wave strip 16), N=128, K chunked by 128.
// LDS: As[64][136] + Bs[128][136] f16 = 52,224 B.
template<int K, int MODE>
__global__ __launch_bounds__(256) void k_gemm(const void* __restrict__ Asrc,
    const hf* __restrict__ Bt, const float* __restrict__ bias,
    float* __restrict__ Cout){
  constexpr int SA = 136;
  __shared__ alignas(16) hf As[64*SA];
  __shared__ alignas(16) hf Bs[128*SA];
  const int tid = threadIdx.x;
  const int w = tid >> 6, lane = tid & 63;
  const int c = lane & 15, q = lane >> 4;
  const int bx = blockIdx.x;
  const int col0 = (MODE==0) ? blockIdx.y*128 : 0;

  float br[8];
  #pragma unroll
  for (int ni=0; ni<8; ni++) br[ni] = bias[col0 + ni*16 + c];

  f32x4 acc[8];
  #pragma unroll
  for (int ni=0; ni<8; ni++) acc[ni] = (f32x4){0.f,0.f,0.f,0.f};

  for (int kc=0; kc<K/128; kc++){
    // ---- stage A chunk (64 rows x 128 k) ----
    if (MODE == 0){
      const float* A = (const float*)Asrc + (long)bx*64*128;
      #pragma unroll
      for (int v=0; v<8; v++){
        int f4 = v*256 + tid;
        int m = f4 >> 5, k4 = (f4 & 31)*4;
        float4 d = *(const float4*)&A[m*128 + k4];
        hf4 h = {(hf)d.x,(hf)d.y,(hf)d.z,(hf)d.w};
        *(hf4*)&As[m*SA + k4] = h;
      }
    } else if (MODE == 1){
      const hf* A = (const hf*)Asrc + (long)bx*64*256;
      #pragma unroll
      for (int v=0; v<4; v++){
        int f8 = v*256 + tid;
        int m = f8 >> 4, k8 = (f8 & 15)*8;
        *(hf8*)&As[m*SA + k8] = *(const hf8*)&A[m*256 + kc*128 + k8];
      }
    } else {
      const float* A = (const float*)Asrc + (long)(bx>>1)*16384;
      const int i0 = (bx & 1)*64;
      #pragma unroll
      for (int v=0; v<8; v++){
        int f4 = v*256 + tid;
        int t = f4 >> 4, i4 = (f4 & 15)*4;
        float4 d = *(const float4*)&A[t*128 + i0 + i4];
        As[(i4+0)*SA + t] = (hf)d.x;
        As[(i4+1)*SA + t] = (hf)d.y;
        As[(i4+2)*SA + t] = (hf)d.z;
        As[(i4+3)*SA + t] = (hf)d.w;
      }
    }
    // ---- stage B chunk (128 n x 128 k), Bt is f16 [n][K] ----
    #pragma unroll
    for (int v=0; v<8; v++){
      int f8 = v*256 + tid;
      int n = f8 >> 4, k8 = (f8 & 15)*8;
      *(hf8*)&Bs[n*SA + k8] = *(const hf8*)&Bt[(col0+n)*K + kc*128 + k8];
    }
    __syncthreads();
    // ---- MFMA ----
    #pragma unroll
    for (int kk=0; kk<4; kk++){
      hf8 a = *(const hf8*)&As[(w*16 + c)*SA + kk*32 + q*8];
      #pragma unroll
      for (int ni=0; ni<8; ni++){
        hf8 b = *(const hf8*)&Bs[(ni*16 + c)*SA + kk*32 + q*8];
        acc[ni] = __builtin_amdgcn_mfma_f32_16x16x32_f16(a, b, acc[ni], 0, 0, 0);
      }
    }
    __syncthreads();
  }
  // ---- epilogue ----
  #pragma unroll
  for (int ni=0; ni<8; ni++){
    #pragma unroll
    for (int r=0; r<4; r++){
      int rloc = w*16 + q*4 + r;
      int col = col0 + ni*16 + c;
      float val = acc[ni][r] + br[ni];
      int addr;
      if (MODE == 0){
        int R = bx*64 + rloc;
        int b_ = R >> 7, t_ = R & 127;
        addr = (t_*512 + b_)*256 + col;
      } else if (MODE == 1){
        int R = bx*64 + rloc;
        addr = R*128 + col;
        val = fast_exp2(C2L*val);
      } else {
        int b_ = bx >> 1, i_ = (bx & 1)*64 + rloc;
        addr = b_*16384 + i_*128 + col;
        val = fast_exp2(C2L*val);
      }
      Cout[addr] = val;
    }
  }
}

// ---------------- recurrence (MFMA, 16 waves, operand-swapped) ----------------
// 32 blocks x 1024 thr (16 waves = 4/SIMD). Block owns batches
// [16*bx,16*bx+16); wave w owns out-cols [16w,16w+16).
// D = Wh^T (A, 32 VGPR/lane) x h^T (B, from LDS). Lane (c,q) gets
// D[oc=16w+4q+r][batch=c]: packed hf4 LDS write + direct hf4 Hb export +
// float4 xw add. h[16 batches][256] hf in LDS, slot-swizzle slot^=(batch&7):
// B-frag reads and packed writes both 2-way max (free).
// dist-2 xw prefetch; raw lgkm-only barrier (no vmcnt drain), 1/step.
__global__ __launch_bounds__(1024, 4) void k_rnn(const float* __restrict__ h0,
    const float* __restrict__ Wh, const float* __restrict__ xw,
    hf* __restrict__ Hb){
  __shared__ alignas(16) char hs[2*8192];   // [parity][16 batches x 512B]
  const int tid = threadIdx.x;
  const int w = tid >> 6, lane = tid & 63;
  const int c = lane & 15, q = lane >> 4;
  const int b0 = blockIdx.x * 16;
  const int oc0 = w*16 + 4*q;                // this lane's 4 out-cols
  // ---- Wh as A-frags: aw[kc][e] = Wh[kc*32+q*8+e][w*16+c] ----
  hf8 aw[8];
  #pragma unroll
  for (int kc=0; kc<8; kc++){
    #pragma unroll
    for (int e=0; e<8; e++){
      aw[kc][e] = (hf)Wh[(kc*32 + q*8 + e)*256 + w*16 + c];
    }
  }
  // ---- stage h0 -> hs[parity 0], swizzled [batch][hcol] ----
  if (tid < 512){
    int m = tid >> 5, s8 = tid & 31;         // batch row, 16B slot
    const float* src = &h0[(b0 + m)*256 + s8*8];
    float4 d0 = *(const float4*)&src[0];
    float4 d1 = *(const float4*)&src[4];
    hf8 hv = {(hf)d0.x,(hf)d0.y,(hf)d0.z,(hf)d0.w,
              (hf)d1.x,(hf)d1.y,(hf)d1.z,(hf)d1.w};
    *(hf8*)&hs[m*512 + ((s8 ^ (m & 7)) << 4)] = hv;
  }
  // ---- prologue: xw for t=0 (xA) and t=1 (xB) ----
  float4 xA = *(const float4*)&xw[(0*512 + b0 + c)*256 + oc0];
  float4 xB = *(const float4*)&xw[(1*512 + b0 + c)*256 + oc0];
  __syncthreads();
  #pragma unroll 1
  for (int t=0; t<128; t+=2){
    #pragma unroll
    for (int half=0; half<2; half++){
      const int T = t + half;
      const int p = T & 1;
      // ---- h B-frags from LDS (swizzled, 2-way free) ----
      hf8 hb[8];
      #pragma unroll
      for (int kc=0; kc<8; kc++)
        hb[kc] = *(const hf8*)&hs[p*8192 + c*512
                                  + ((((kc<<2)|q) ^ (c & 7)) << 4)];
      // ---- 2 independent 4-deep MFMA chains: D = Wh^T x h^T ----
      f32x4 al = (f32x4){0.f,0.f,0.f,0.f}, ah = al;
      #pragma unroll
      for (int kc=0; kc<4; kc++){
        al = __builtin_amdgcn_mfma_f32_16x16x32_f16(aw[kc],   hb[kc],   al,0,0,0);
        ah = __builtin_amdgcn_mfma_f32_16x16x32_f16(aw[kc+4], hb[kc+4], ah,0,0,0);
      }
      // ---- reload xw for T+2 (consumed 2 steps later) ----
      float4 nv = (T+2 < 128)
        ? *(const float4*)&xw[((T+2)*512 + b0 + c)*256 + oc0]
        : (float4){0.f,0.f,0.f,0.f};
      // ---- tanh (paired rcp) + packed LDS write + direct Hb export ----
      {
        float4 xv = half ? xB : xA;
        float v0 = al[0] + ah[0] + xv.x;
        float v1 = al[1] + ah[1] + xv.y;
        float v2 = al[2] + ah[2] + xv.z;
        float v3 = al[3] + ah[3] + xv.w;
        float ea = fast_exp2(v0*C2L) + 1.f;
        float eb = fast_exp2(v1*C2L) + 1.f;
        float R0 = fast_rcp(ea*eb);
        float ec = fast_exp2(v2*C2L) + 1.f;
        float ed = fast_exp2(v3*C2L) + 1.f;
        float R1 = fast_rcp(ec*ed);
        hf4 h4 = {(hf)fmaf(-2.f*eb, R0, 1.f), (hf)fmaf(-2.f*ea, R0, 1.f),
                  (hf)fmaf(-2.f*ed, R1, 1.f), (hf)fmaf(-2.f*ec, R1, 1.f)};
        *(hf4*)&hs[(p^1)*8192 + c*512
                   + (((oc0 >> 3) ^ (c & 7)) << 4) + (oc0 & 7)*2] = h4;
        *(hf4*)&Hb[(T*512 + b0 + c)*256 + oc0] = h4;
        if (half) xB = nv; else xA = nv;
      }
      // ---- raw barrier: LDS ordering only, no vmcnt drain ----
      asm volatile("s_waitcnt lgkmcnt(0)\n\ts_barrier" ::: "memory");
    }
  }
}

// ---------------- attention + softmax + scale ----------------
// grid (512 b, 4 t-tiles), 512 threads. Thread = (i, tau-quarter g of 32).
// P quarter in registers (8 float4 = 32 VGPR). Q tile (32 t) in LDS.
// 4-way rcp: w0/u+w1/v+w2/x+w3/y = (n01*d23+n23*d01)*rcp(d01*d23)
// -> 1 rcp per 4 taus. 4 timesteps per sweep; 2 barriers per sweep.
// No max in softmax (|e| <= sum|wv| ~ 5).
__global__ __launch_bounds__(512, 4) void k_attn(const float* __restrict__ P,
    const float* __restrict__ Qm, const float* __restrict__ Wv,
    const float* __restrict__ data, float* __restrict__ out){
  __shared__ alignas(16) float qs[32*128];          // [tt][tau] 16KB
  __shared__ alignas(16) float wvs[128];
  __shared__ alignas(16) float epart[2][4][4][128]; // [parity][quar][tl][i] 16KB
  __shared__ float red[2][4][2];                    // [parity][tl][half]
  const int b = blockIdx.x, tile = blockIdx.y;
  const int tid = threadIdx.x;
  const int i = tid & 127, g = tid >> 7;            // i, tau-quarter 0..3
  const int t0 = tile*32;
  if (tid < 128) wvs[tid] = -2.f*Wv[tid];
  #pragma unroll
  for (int v=0; v<2; v++){
    int flat = v*2048 + tid*4;
    int tt = flat >> 7, c = flat & 127;
    *(float4*)&qs[flat] = *(const float4*)&Qm[((t0+tt)*512 + b)*128 + c];
  }
  float4 p4[8];
  const float* prow = P + b*16384 + i*128 + g*32;
  #pragma unroll
  for (int v=0; v<8; v++) p4[v] = *(const float4*)&prow[v*4];
  __syncthreads();
  for (int tp=0; tp<8; tp++){
    const int pp = tp & 1;
    const float* qb  = &qs[(4*tp)*128 + g*32];
    const float* wvr = &wvs[g*32];
    float acc0=0.f, acc1=0.f, acc2=0.f, acc3=0.f;
    #pragma unroll
    for (int mm=0; mm<8; mm++){
      float4 Pv = p4[mm];
      float4 wv = *(const float4*)&wvr[mm*4];
      #pragma unroll
      for (int tl=0; tl<4; tl++){
        float4 qq = *(const float4*)&qb[tl*128 + mm*4];
        float u = fmaf(Pv.x, qq.x, 1.f), v = fmaf(Pv.y, qq.y, 1.f);
        float x = fmaf(Pv.z, qq.z, 1.f), y = fmaf(Pv.w, qq.w, 1.f);
        float d01 = u*v, d23 = x*y;
        float n01 = fmaf(wv.x, v, wv.y*u);
        float n23 = fmaf(wv.z, y, wv.w*x);
        float N = fmaf(n01, d23, n23*d01);
        float r = fast_rcp(d01*d23);
        float term = N*r;
        if (tl==0) acc0 += term;
        else if (tl==1) acc1 += term;
        else if (tl==2) acc2 += term;
        else acc3 += term;
      }
    }
    epart[pp][g][0][i] = acc0;
    epart[pp][g][1][i] = acc1;
    epart[pp][g][2][i] = acc2;
    epart[pp][g][3][i] = acc3;
    __syncthreads();
    // thread handles tl = g for the reduction + output
    float e = epart[pp][0][g][i] + epart[pp][1][g][i]
            + epart[pp][2][g][i] + epart[pp][3][g][i];
    float pe = fast_exp2(e*L2E);
    float sm = pe;
    #pragma unroll
    for (int off=32; off; off>>=1) sm += __shfl_xor(sm, off);
    if ((tid & 63) == 0) red[pp][g][(tid>>6)&1] = sm;
    __syncthreads();
    float ssum = red[pp][g][0] + red[pp][g][1];
    float alpha = pe * fast_rcp(ssum);
    int t = t0 + 4*tp + g;
    int base = (t*512 + b)*128 + i;
    out[base] = data[base]*alpha;
  }
}

extern "C" void kernel_launch(void* const* d_in, const int* in_sizes, int n_in,
                              void* d_out, int out_size, void* d_ws, size_t ws_size,
                              hipStream_t stream) {
  const float* data = (const float*)d_in[0];
  const float* h0   = (const float*)d_in[1];
  const float* Wx   = (const float*)d_in[2];
  const float* Wh   = (const float*)d_in[3];
  const float* bb   = (const float*)d_in[4];
  const float* W1   = (const float*)d_in[5];
  const float* b1   = (const float*)d_in[6];
  const float* W2   = (const float*)d_in[7];
  const float* b2   = (const float*)d_in[8];
  const float* Wv   = (const float*)d_in[9];
  // d_in[10] = bv: softmax-invariant constant, dropped. d_in[11] = n (128).
  float* wsp = (float*)d_ws;
  float* P   = wsp;                         //  8,388,608 f
  float* xwQ = wsp + 8388608;               // 16,777,216 f (xw, then reused as Q)
  hf*    Hbf = (hf*)(wsp + 25165824);       // 16,777,216 hf
  hf*    wts = (hf*)(wsp + 33554432);       // 81,920 hf
  const hf* Wxt = wts;                      // [256][128]
  const hf* W2t = wts + 32768;              // [128][256]
  const hf* W1t = wts + 65536;              // [128][128]
  float* out = (float*)d_out;

  hipLaunchKernelGGL(k_prep_w, dim3(320), dim3(256), 0, stream, Wx, W2, W1, wts);
  hipLaunchKernelGGL((k_gemm<128,0>), dim3(1024,2), dim3(256), 0, stream,
                     (const void*)data, Wxt, bb, xwQ);
  hipLaunchKernelGGL((k_gemm<128,2>), dim3(1024),   dim3(256), 0, stream,
                     (const void*)data, W1t, b1, P);
  hipLaunchKernelGGL(k_rnn, dim3(32), dim3(1024), 0, stream, h0, Wh, xwQ, Hbf);
  hipLaunchKernelGGL((k_gemm<256,1>), dim3(1024),   dim3(256), 0, stream,
                     (const void*)Hbf, W2t, b2, xwQ);
  hipLaunchKernelGGL(k_attn, dim3(512, 4), dim3(512), 0, stream, P, xwQ, Wv, data, out);
}